// Round 1
// baseline (932.221 us; speedup 1.0000x reference)
//
#include <hip/hip_runtime.h>
#include <math.h>

#define EPS 1e-5f

// bq in [0,96): b = bq/12, t = bq%12; x1seq row = b*12 + min(t+1, 11)
__device__ __forceinline__ int src_row(int bq) {
    int b = bq / 12, t = bq - b * 12;
    int t2 = (t + 1 < 12) ? (t + 1) : 11;
    return b * 12 + t2;
}

// ---------------- erase0: y0vec[bq][o] = BN(W_e @ mean_n(x) + b_e) ----------------
__global__ __launch_bounds__(256) void erase0_kernel(
    const float* __restrict__ x, const float* __restrict__ w_e,
    const float* __restrict__ b_e, const float* __restrict__ g_e,
    const float* __restrict__ be_e, const float* __restrict__ m_e,
    const float* __restrict__ v_e, float* __restrict__ y0vec)
{
    __shared__ float part[256];
    __shared__ float res[64];
    int bq = blockIdx.x, tid = threadIdx.x;
    int c = tid >> 2, p = tid & 3;
    const float* xb = x + (size_t)bq * 32768 + c * 512 + p * 128;
    float acc = 0.f;
    for (int ii = 0; ii < 128; ii += 4) {
        float4 v = *(const float4*)(xb + ii);
        acc += v.x + v.y + v.z + v.w;
    }
    part[tid] = acc;
    __syncthreads();
    if (p == 0) res[c] = (part[tid] + part[tid+1] + part[tid+2] + part[tid+3]) * (1.f/512.f);
    __syncthreads();
    if (tid < 64) {
        float a = b_e[tid];
        for (int cc = 0; cc < 64; ++cc) a += w_e[tid*64+cc] * res[cc];
        float s = g_e[tid] / sqrtf(v_e[tid] + EPS);
        y0vec[bq*64 + tid] = (a - m_e[tid]) * s + be_e[tid];
    }
}

// ---------------- x0 = x + y0vec broadcast ----------------
__global__ __launch_bounds__(256) void add_vec_kernel(
    const float* __restrict__ x, const float* __restrict__ vec, float* __restrict__ out)
{
    int g = blockIdx.x * 256 + threadIdx.x;   // quad index, total 786432
    int e = g * 4;
    int bq = e >> 15, c = (e >> 9) & 63;
    float4 v = *(const float4*)(x + e);
    float a = vec[bq * 64 + c];
    v.x += a; v.y += a; v.z += a; v.w += a;
    *(float4*)(out + e) = v;
}

// ---------------- column norms: out[bq][i] = sum_c X[row(bq)][c][i]^2 ----------------
__global__ __launch_bounds__(256) void colnorm_kernel(
    const float* __restrict__ X, float* __restrict__ out, int remap)
{
    int g = blockIdx.x * 256 + threadIdx.x;   // 0..49151
    int bq = g >> 9, i = g & 511;
    int row = remap ? src_row(bq) : bq;
    const float* Xb = X + (size_t)row * 32768 + i;
    float acc = 0.f;
    for (int c = 0; c < 64; ++c) { float v = Xb[c * 512]; acc += v * v; }
    out[g] = acc;
}

// ---------------- kNN: top-K of score[j] = 2*dot(x_i,x_j) - xx_j per row ----------------
// grid = 96*8 blocks; block handles 64 rows (itile), streams 8 j-tiles of 64.
template<int K>
__global__ __launch_bounds__(256) void knn_kernel(
    const float* __restrict__ X, const float* __restrict__ xn,
    int* __restrict__ idx_out, int remap)
{
    __shared__ float ldsXi[64 * 64];   // [c][i]
    __shared__ float ldsXj[64 * 64];   // [c][j]
    __shared__ float ldsS[64 * 68];    // [i][j] padded stride 68
    int bq = blockIdx.x >> 3;
    int itile = blockIdx.x & 7;
    int row = remap ? src_row(bq) : bq;
    const float* Xb = X + (size_t)row * 32768;
    int tid = threadIdx.x;
    int ibase = itile * 64;
    for (int p = 0; p < 16; ++p) {
        int t = p * 256 + tid;
        int c = t >> 6, il = t & 63;
        ldsXi[t] = Xb[c * 512 + ibase + il];
    }
    float kv[K]; int kj[K];
    #pragma unroll
    for (int q = 0; q < K; ++q) { kv[q] = -3.4e38f; kj[q] = 0; }
    int tj = tid & 15, ti = tid >> 4;
    for (int jt = 0; jt < 8; ++jt) {
        __syncthreads();   // protect ldsS (prev scan) / ldsXj reload
        int jbase = jt * 64;
        for (int p = 0; p < 16; ++p) {
            int t = p * 256 + tid;
            int c = t >> 6, jl = t & 63;
            ldsXj[t] = Xb[c * 512 + jbase + jl];
        }
        __syncthreads();
        float4 xn4 = *(const float4*)&xn[bq * 512 + jbase + 4 * tj];
        float acc[4][4];
        #pragma unroll
        for (int a = 0; a < 4; ++a)
            #pragma unroll
            for (int b2 = 0; b2 < 4; ++b2) acc[a][b2] = 0.f;
        for (int c = 0; c < 64; ++c) {
            float4 av = *(float4*)&ldsXi[c * 64 + 4 * ti];
            float4 bv = *(float4*)&ldsXj[c * 64 + 4 * tj];
            acc[0][0] += av.x * bv.x; acc[0][1] += av.x * bv.y; acc[0][2] += av.x * bv.z; acc[0][3] += av.x * bv.w;
            acc[1][0] += av.y * bv.x; acc[1][1] += av.y * bv.y; acc[1][2] += av.y * bv.z; acc[1][3] += av.y * bv.w;
            acc[2][0] += av.z * bv.x; acc[2][1] += av.z * bv.y; acc[2][2] += av.z * bv.z; acc[2][3] += av.z * bv.w;
            acc[3][0] += av.w * bv.x; acc[3][1] += av.w * bv.y; acc[3][2] += av.w * bv.z; acc[3][3] += av.w * bv.w;
        }
        #pragma unroll
        for (int a = 0; a < 4; ++a) {
            float4 sv;
            sv.x = 2.f * acc[a][0] - xn4.x;
            sv.y = 2.f * acc[a][1] - xn4.y;
            sv.z = 2.f * acc[a][2] - xn4.z;
            sv.w = 2.f * acc[a][3] - xn4.w;
            *(float4*)&ldsS[(4 * ti + a) * 68 + 4 * tj] = sv;
        }
        __syncthreads();
        if (tid < 64) {
            for (int j = 0; j < 64; ++j) {
                float v = ldsS[tid * 68 + j];
                if (v > kv[0]) {        // strict >: earlier j wins ties (matches lax.top_k)
                    bool placed = false;
                    #pragma unroll
                    for (int q = 0; q < K; ++q) {
                        if (!placed) {
                            bool shift = (q + 1 < K) && (kv[q + 1] < v);
                            if (shift) { kv[q] = kv[q + 1]; kj[q] = kj[q + 1]; }
                            else { kv[q] = v; kj[q] = jbase + j; placed = true; }
                        }
                    }
                }
            }
        }
    }
    if (tid < 64) {
        int* op = idx_out + ((size_t)bq * 512 + ibase + tid) * 16;
        #pragma unroll
        for (int q = 0; q < K; ++q) op[q] = kj[q];
    }
}

// ---------------- AB[bq] = [W1; W2-W1] (128x64) @ X[bq] (64x512) ----------------
// grid = 96*8; block computes [128 o][64 i] tile; thread: 8o x 4i.
__global__ __launch_bounds__(256) void gemm_kernel(
    const float* __restrict__ X, const float* __restrict__ W,
    float* __restrict__ AB, int remap)
{
    __shared__ float ldsW[64 * 128];   // [c][o]
    __shared__ float ldsX[64 * 64];    // [c][i]
    int bq = blockIdx.x >> 3, itile = blockIdx.x & 7;
    int tid = threadIdx.x;
    int row = remap ? src_row(bq) : bq;
    const float* Xb = X + (size_t)row * 32768;
    for (int p = 0; p < 32; ++p) {
        int t = p * 256 + tid;         // t = c*128 + o
        int c = t >> 7, o = t & 127;
        float val;
        if (o < 64) val = W[o * 128 + c];                                  // W1
        else        val = W[(o - 64) * 128 + 64 + c] - W[(o - 64) * 128 + c]; // W2-W1
        ldsW[t] = val;
    }
    int ibase = itile * 64;
    for (int p = 0; p < 16; ++p) {
        int t = p * 256 + tid;
        int c = t >> 6, il = t & 63;
        ldsX[t] = Xb[c * 512 + ibase + il];
    }
    __syncthreads();
    int tj = tid & 15, to = tid >> 4;
    int i0 = 4 * tj, o0 = 8 * to;
    float acc[8][4];
    #pragma unroll
    for (int a = 0; a < 8; ++a)
        #pragma unroll
        for (int b2 = 0; b2 < 4; ++b2) acc[a][b2] = 0.f;
    for (int c = 0; c < 64; ++c) {
        float4 xv  = *(float4*)&ldsX[c * 64 + i0];
        float4 w0v = *(float4*)&ldsW[c * 128 + o0];
        float4 w1v = *(float4*)&ldsW[c * 128 + o0 + 4];
        acc[0][0] += w0v.x * xv.x; acc[0][1] += w0v.x * xv.y; acc[0][2] += w0v.x * xv.z; acc[0][3] += w0v.x * xv.w;
        acc[1][0] += w0v.y * xv.x; acc[1][1] += w0v.y * xv.y; acc[1][2] += w0v.y * xv.z; acc[1][3] += w0v.y * xv.w;
        acc[2][0] += w0v.z * xv.x; acc[2][1] += w0v.z * xv.y; acc[2][2] += w0v.z * xv.z; acc[2][3] += w0v.z * xv.w;
        acc[3][0] += w0v.w * xv.x; acc[3][1] += w0v.w * xv.y; acc[3][2] += w0v.w * xv.z; acc[3][3] += w0v.w * xv.w;
        acc[4][0] += w1v.x * xv.x; acc[4][1] += w1v.x * xv.y; acc[4][2] += w1v.x * xv.z; acc[4][3] += w1v.x * xv.w;
        acc[5][0] += w1v.y * xv.x; acc[5][1] += w1v.y * xv.y; acc[5][2] += w1v.y * xv.z; acc[5][3] += w1v.y * xv.w;
        acc[6][0] += w1v.z * xv.x; acc[6][1] += w1v.z * xv.y; acc[6][2] += w1v.z * xv.z; acc[6][3] += w1v.z * xv.w;
        acc[7][0] += w1v.w * xv.x; acc[7][1] += w1v.w * xv.y; acc[7][2] += w1v.w * xv.z; acc[7][3] += w1v.w * xv.w;
    }
    float* out = AB + (size_t)bq * 65536 + ibase + i0;
    #pragma unroll
    for (int a = 0; a < 8; ++a) {
        float4 sv; sv.x = acc[a][0]; sv.y = acc[a][1]; sv.z = acc[a][2]; sv.w = acc[a][3];
        *(float4*)(out + (size_t)(o0 + a) * 512) = sv;
    }
}

// ---------------- branch epilogue: y = lrelu(s*(max_k A[o,idx[i,k]] + Bv[o,i]) + t) ----------------
// then p[o]=max_i y, p[64+o]=mean_i y. ACC=1 accumulates into out_p.
template<int ACC>
__global__ __launch_bounds__(256) void branch_reduce_kernel(
    const float* __restrict__ AB, const int* __restrict__ idx,
    const float* __restrict__ g, const float* __restrict__ bb,
    const float* __restrict__ mm, const float* __restrict__ vv,
    float* __restrict__ out_p, float* __restrict__ vec_out)
{
    __shared__ float ldsA[512];
    __shared__ int ldsIdx[512 * 10];
    __shared__ float ldsRed[8];
    __shared__ float sS[64], sT[64];
    int bq = blockIdx.x, tid = threadIdx.x;
    for (int p = 0; p < 20; ++p) {
        int t = p * 256 + tid;
        int i = t / 10, q = t - i * 10;
        ldsIdx[t] = idx[((size_t)bq * 512 + i) * 16 + q];
    }
    if (tid < 64) {
        float sc = g[tid] / sqrtf(vv[tid] + EPS);
        sS[tid] = sc;
        sT[tid] = bb[tid] - mm[tid] * sc;
    }
    __syncthreads();
    const float* ABb = AB + (size_t)bq * 65536;
    for (int o = 0; o < 64; ++o) {
        const float* Arow = ABb + o * 512;
        ldsA[tid] = Arow[tid];
        ldsA[tid + 256] = Arow[tid + 256];
        __syncthreads();
        const float* Brow = ABb + (64 + o) * 512;
        float s = sS[o], tsh = sT[o];
        float mymax = -3.4e38f, mysum = 0.f;
        for (int ii = tid; ii < 512; ii += 256) {
            const int* ip = &ldsIdx[ii * 10];
            float mx = ldsA[ip[0]];
            #pragma unroll
            for (int q = 1; q < 10; ++q) mx = fmaxf(mx, ldsA[ip[q]]);
            float val = (mx + Brow[ii]) * s + tsh;
            float y = val > 0.f ? val : 0.2f * val;
            mymax = fmaxf(mymax, y);
            mysum += y;
        }
        #pragma unroll
        for (int off = 32; off >= 1; off >>= 1) {
            mymax = fmaxf(mymax, __shfl_down(mymax, off));
            mysum += __shfl_down(mysum, off);
        }
        __syncthreads();
        int wv = tid >> 6, ln = tid & 63;
        if (ln == 0) { ldsRed[wv] = mymax; ldsRed[4 + wv] = mysum; }
        __syncthreads();
        if (tid == 0) {
            float M = fmaxf(fmaxf(ldsRed[0], ldsRed[1]), fmaxf(ldsRed[2], ldsRed[3]));
            float S = ldsRed[4] + ldsRed[5] + ldsRed[6] + ldsRed[7];
            float* po = out_p + bq * 128;
            if (ACC) {
                po[o] += M;
                po[64 + o] += S * (1.f / 512.f);
            } else {
                po[o] = M;
                po[64 + o] = S * (1.f / 512.f);
                vec_out[bq * 64 + o] = M;
            }
        }
    }
}

// ---------------- corre_binar: f, masks ----------------
__global__ __launch_bounds__(256) void corre_kernel(
    const float* __restrict__ x, const float* __restrict__ x0vec,
    const float* __restrict__ w_reduce, const int* __restrict__ idx8,
    float* __restrict__ fbuf, float* __restrict__ masks)
{
    __shared__ float sxv[64], sq[64], ss[512], sfk[512];
    int bq = blockIdx.x, tid = threadIdx.x;
    int row = src_row(bq);
    const float* Xb = x + (size_t)row * 32768;
    if (tid < 64) sxv[tid] = x0vec[bq * 64 + tid];
    __syncthreads();
    if (tid < 64) {
        float a = 0.f;
        for (int c = 0; c < 64; ++c) a += w_reduce[tid * 64 + c] * sxv[c];
        sq[tid] = a;
    }
    __syncthreads();
    for (int i = tid; i < 512; i += 256) {
        float a = 0.f;
        for (int c = 0; c < 64; ++c) a += sq[c] * Xb[c * 512 + i];
        a *= 0.125f;                    // 1/sqrt(64)
        ss[i] = a;
        fbuf[bq * 512 + i] = a;
    }
    __syncthreads();
    for (int i = tid; i < 512; i += 256) {
        float a = ss[i];
        const int* ip = idx8 + ((size_t)bq * 512 + i) * 16;
        for (int q = 0; q < 8; ++q) a += ss[ip[q]];
        sfk[i] = a;
    }
    masks[bq * 512 + tid] = 1.0f;
    masks[bq * 512 + tid + 256] = 1.0f;
    __syncthreads();
    if (tid == 0) {
        float best = sfk[0]; int bi = 0;
        for (int i = 1; i < 512; ++i) if (sfk[i] > best) { best = sfk[i]; bi = i; }
        masks[bq * 512 + bi] = 0.f;
        const int* ip = idx8 + ((size_t)bq * 512 + bi) * 16;
        for (int q = 0; q < 8; ++q) masks[bq * 512 + ip[q]] = 0.f;
    }
}

// ---------------- erase1: x1e = x1seq*mask + BN(W_e @ softmax-pooled + b_e) ----------------
__global__ __launch_bounds__(256) void erase1_kernel(
    const float* __restrict__ x, const float* __restrict__ masks,
    const float* __restrict__ fbuf,
    const float* __restrict__ w_e, const float* __restrict__ b_e,
    const float* __restrict__ g_e, const float* __restrict__ be_e,
    const float* __restrict__ m_e, const float* __restrict__ v_e,
    float* __restrict__ x1e)
{
    __shared__ float sw[512];
    __shared__ float smk[512];
    __shared__ float red[256];
    __shared__ float sres[64];
    __shared__ float sy[64];
    int bq = blockIdx.x, tid = threadIdx.x;
    int row = src_row(bq);
    const float* Xb = x + (size_t)row * 32768;
    float f0 = fbuf[bq * 512 + tid], f1 = fbuf[bq * 512 + tid + 256];
    float mk0 = masks[bq * 512 + tid], mk1 = masks[bq * 512 + tid + 256];
    smk[tid] = mk0; smk[tid + 256] = mk1;
    float s0 = f0 - (1.f - mk0) * 1e8f, s1 = f1 - (1.f - mk1) * 1e8f;
    red[tid] = fmaxf(s0, s1);
    __syncthreads();
    for (int off = 128; off >= 1; off >>= 1) {
        if (tid < off) red[tid] = fmaxf(red[tid], red[tid + off]);
        __syncthreads();
    }
    float mx = red[0];
    __syncthreads();
    float e0 = expf(s0 - mx), e1 = expf(s1 - mx);
    red[tid] = e0 + e1;
    __syncthreads();
    for (int off = 128; off >= 1; off >>= 1) {
        if (tid < off) red[tid] = red[tid] + red[tid + off];
        __syncthreads();
    }
    float inv = 1.f / red[0];
    __syncthreads();
    sw[tid] = e0 * inv; sw[tid + 256] = e1 * inv;
    __syncthreads();
    // res[c] = sum_i x1seq[c][i] * w[i]
    int c = tid >> 2, p = tid & 3;
    {
        float a = 0.f;
        const float* xr = Xb + c * 512 + p * 128;
        const float* wr = &sw[p * 128];
        for (int ii = 0; ii < 128; ++ii) a += xr[ii] * wr[ii];
        red[tid] = a;
    }
    __syncthreads();
    if (p == 0) sres[c] = red[tid] + red[tid + 1] + red[tid + 2] + red[tid + 3];
    __syncthreads();
    if (tid < 64) {
        float a = b_e[tid];
        for (int cc = 0; cc < 64; ++cc) a += w_e[tid * 64 + cc] * sres[cc];
        float sc = g_e[tid] / sqrtf(v_e[tid] + EPS);
        sy[tid] = (a - m_e[tid]) * sc + be_e[tid];
    }
    __syncthreads();
    float* ob = x1e + (size_t)bq * 32768;
    for (int p2 = 0; p2 < 128; ++p2) {
        int e = p2 * 256 + tid;
        int cc = e >> 9, i = e & 511;
        ob[e] = Xb[e] * smk[i] + sy[cc];
    }
}

extern "C" void kernel_launch(void* const* d_in, const int* in_sizes, int n_in,
                              void* d_out, int out_size, void* d_ws, size_t ws_size,
                              hipStream_t stream)
{
    const float* x        = (const float*)d_in[0];
    const float* w_reduce = (const float*)d_in[1];
    const float* w_erase  = (const float*)d_in[2];
    const float* b_erase  = (const float*)d_in[3];
    const float* g_erase  = (const float*)d_in[4];
    const float* be_erase = (const float*)d_in[5];
    const float* m_erase  = (const float*)d_in[6];
    const float* v_erase  = (const float*)d_in[7];
    const float* w0 = (const float*)d_in[8];
    const float* g0 = (const float*)d_in[9];
    const float* b0 = (const float*)d_in[10];
    const float* m0 = (const float*)d_in[11];
    const float* v0 = (const float*)d_in[12];
    const float* w1 = (const float*)d_in[13];
    const float* g1 = (const float*)d_in[14];
    const float* b1 = (const float*)d_in[15];
    const float* m1 = (const float*)d_in[16];
    const float* v1 = (const float*)d_in[17];
    float* out = (float*)d_out;
    char* ws = (char*)d_ws;

    float* xbuf  = (float*)(ws);                 // 12.58 MB: x0, later x1e
    float* AB    = (float*)(ws + 12582912);      // 25.17 MB: [96][128][512], reused
    int*   idxA  = (int*)(ws + 37748736);        // 3.15 MB: k=10 idx (stride 16), reused
    int*   idx8  = (int*)(ws + 40894464);        // 3.15 MB: k=8 idx
    float* xn    = (float*)(ws + 44040192);      // 192 KB: col norms, reused
    float* y0vec = (float*)(ws + 44236800);      // 24 KB
    float* x0vec = (float*)(ws + 44261376);      // 24 KB
    float* fbuf  = (float*)(ws + 44285952);      // 192 KB
    float* masks = (float*)(ws + 44482560);      // 192 KB  (total ~44.7 MB)

    (void)in_sizes; (void)n_in; (void)out_size; (void)ws_size;

    // x0 = erase(x, ones, ones)
    erase0_kernel<<<96, 256, 0, stream>>>(x, w_erase, b_erase, g_erase, be_erase, m_erase, v_erase, y0vec);
    add_vec_kernel<<<3072, 256, 0, stream>>>(x, y0vec, xbuf);
    // branch 0
    colnorm_kernel<<<192, 256, 0, stream>>>(xbuf, xn, 0);
    knn_kernel<10><<<768, 256, 0, stream>>>(xbuf, xn, idxA, 0);
    gemm_kernel<<<768, 256, 0, stream>>>(xbuf, w0, AB, 0);
    branch_reduce_kernel<0><<<96, 256, 0, stream>>>(AB, idxA, g0, b0, m0, v0, out, x0vec);
    // corre_binar on x1seq (x with t-shift remap)
    colnorm_kernel<<<192, 256, 0, stream>>>(x, xn, 1);
    knn_kernel<8><<<768, 256, 0, stream>>>(x, xn, idx8, 1);
    corre_kernel<<<96, 256, 0, stream>>>(x, x0vec, w_reduce, idx8, fbuf, masks);
    // x1e = erase(x1seq, masks, f)
    erase1_kernel<<<96, 256, 0, stream>>>(x, masks, fbuf, w_erase, b_erase, g_erase, be_erase, m_erase, v_erase, xbuf);
    // branch 1
    colnorm_kernel<<<192, 256, 0, stream>>>(xbuf, xn, 0);
    knn_kernel<10><<<768, 256, 0, stream>>>(xbuf, xn, idxA, 0);
    gemm_kernel<<<768, 256, 0, stream>>>(xbuf, w1, AB, 0);
    branch_reduce_kernel<1><<<96, 256, 0, stream>>>(AB, idxA, g1, b1, m1, v1, out, nullptr);
}

// Round 2
// 735.651 us; speedup vs baseline: 1.2672x; 1.2672x over previous
//
#include <hip/hip_runtime.h>
#include <math.h>

#define EPS 1e-5f

typedef _Float16 half8 __attribute__((ext_vector_type(8)));
typedef float f32x4 __attribute__((ext_vector_type(4)));

// bq in [0,96): b = bq/12, t = bq%12; x1seq row = b*12 + min(t+1, 11)
__device__ __forceinline__ int src_row(int bq) {
    int b = bq / 12, t = bq - b * 12;
    int t2 = (t + 1 < 12) ? (t + 1) : 11;
    return b * 12 + t2;
}

// ---------------- erase0: y0vec[bq][o] = BN(W_e @ mean_n(x) + b_e) ----------------
__global__ __launch_bounds__(256) void erase0_kernel(
    const float* __restrict__ x, const float* __restrict__ w_e,
    const float* __restrict__ b_e, const float* __restrict__ g_e,
    const float* __restrict__ be_e, const float* __restrict__ m_e,
    const float* __restrict__ v_e, float* __restrict__ y0vec)
{
    __shared__ float part[256];
    __shared__ float res[64];
    int bq = blockIdx.x, tid = threadIdx.x;
    int c = tid >> 2, p = tid & 3;
    const float* xb = x + (size_t)bq * 32768 + c * 512 + p * 128;
    float acc = 0.f;
    for (int ii = 0; ii < 128; ii += 4) {
        float4 v = *(const float4*)(xb + ii);
        acc += v.x + v.y + v.z + v.w;
    }
    part[tid] = acc;
    __syncthreads();
    if (p == 0) res[c] = (part[tid] + part[tid+1] + part[tid+2] + part[tid+3]) * (1.f/512.f);
    __syncthreads();
    if (tid < 64) {
        float a = b_e[tid];
        for (int cc = 0; cc < 64; ++cc) a += w_e[tid*64+cc] * res[cc];
        float s = g_e[tid] / sqrtf(v_e[tid] + EPS);
        y0vec[bq*64 + tid] = (a - m_e[tid]) * s + be_e[tid];
    }
}

// ---------------- prep: fp16 split (h,l) in [n][c] layout + exact fp32 colnorms ----------------
// X fp32 [rows][64][512]; optional vec add (x0), optional t-remap (x1seq).
// grid = 96*8 (64 cols per block)
__global__ __launch_bounds__(256) void prep_kernel(
    const float* __restrict__ X, const float* __restrict__ vec, int remap,
    _Float16* __restrict__ H, _Float16* __restrict__ L, float* __restrict__ xn)
{
    __shared__ float lds[64 * 65];     // [c][col] pad
    __shared__ float xnp[4 * 64];
    int bq = blockIdx.x >> 3, ct = blockIdx.x & 7;
    int row = remap ? src_row(bq) : bq;
    const float* Xb = X + (size_t)row * 32768 + ct * 64;
    int tid = threadIdx.x;
    for (int p = 0; p < 16; ++p) {
        int t = p * 256 + tid;
        int c = t >> 6, col = t & 63;
        float v = Xb[c * 512 + col];
        if (vec) v += vec[bq * 64 + c];
        lds[c * 65 + col] = v;
    }
    __syncthreads();
    int col = tid & 63, g = tid >> 6;       // g: group of 16 channels
    half8 hv[2], lv[2];
    float s = 0.f;
    #pragma unroll
    for (int k = 0; k < 16; ++k) {
        int c = g * 16 + k;
        float v = lds[c * 65 + col];
        _Float16 h = (_Float16)v;
        _Float16 lo = (_Float16)(v - (float)h);
        hv[k >> 3][k & 7] = h;
        lv[k >> 3][k & 7] = lo;
        s += v * v;
    }
    size_t obase = ((size_t)bq * 512 + ct * 64 + col) * 64 + g * 16;
    *(half8*)(H + obase) = hv[0];
    *(half8*)(H + obase + 8) = hv[1];
    *(half8*)(L + obase) = lv[0];
    *(half8*)(L + obase + 8) = lv[1];
    xnp[g * 64 + col] = s;
    __syncthreads();
    if (tid < 64)
        xn[bq * 512 + ct * 64 + tid] =
            xnp[tid] + xnp[64 + tid] + xnp[128 + tid] + xnp[192 + tid];
}

// ---------------- kNN via split-fp16 MFMA ----------------
// score[j] = 2*dot(x_i,x_j) - xn[j]; top-K sets match fp32 (error ~1e-6).
// grid = 96*8; wave w owns rows [itile*64 + w*16, +16); lanes: row=l&15, quarter=l>>4.
template<int K>
__global__ __launch_bounds__(256) void knn_mfma_kernel(
    const _Float16* __restrict__ H, const _Float16* __restrict__ L,
    const float* __restrict__ xn, int* __restrict__ idx_out)
{
    __shared__ float ldsS[4][16 * 66];
    __shared__ float ldsMV[4][16 * 4 * K];
    __shared__ int   ldsMJ[4][16 * 4 * K];
    int bq = blockIdx.x >> 3, itile = blockIdx.x & 7;
    int tid = threadIdx.x, w = tid >> 6, l = tid & 63;
    int lane16 = l & 15, quad = l >> 4;
    const size_t base = (size_t)bq * 512 * 64;
    int irow = itile * 64 + w * 16 + lane16;
    // A fragments in registers (2 K-steps x {h,l})
    const _Float16* Ha = H + base + (size_t)irow * 64 + quad * 8;
    const _Float16* La = L + base + (size_t)irow * 64 + quad * 8;
    half8 Ah0 = *(const half8*)(Ha);
    half8 Ah1 = *(const half8*)(Ha + 32);
    half8 Al0 = *(const half8*)(La);
    half8 Al1 = *(const half8*)(La + 32);
    float kv[K]; int kj[K];
    #pragma unroll
    for (int q = 0; q < K; ++q) { kv[q] = -3.4e38f; kj[q] = 0; }
    float* Sw = ldsS[w];
    for (int jt = 0; jt < 8; ++jt) {
        int jbase = jt * 64;
        #pragma unroll
        for (int js = 0; js < 4; ++js) {
            int j = jbase + js * 16 + lane16;
            const _Float16* hj = H + base + (size_t)j * 64 + quad * 8;
            const _Float16* lj = L + base + (size_t)j * 64 + quad * 8;
            half8 Bh0 = *(const half8*)(hj);
            half8 Bh1 = *(const half8*)(hj + 32);
            half8 Bl0 = *(const half8*)(lj);
            half8 Bl1 = *(const half8*)(lj + 32);
            f32x4 acc = {0.f, 0.f, 0.f, 0.f};
            acc = __builtin_amdgcn_mfma_f32_16x16x32_f16(Ah0, Bh0, acc, 0, 0, 0);
            acc = __builtin_amdgcn_mfma_f32_16x16x32_f16(Ah1, Bh1, acc, 0, 0, 0);
            acc = __builtin_amdgcn_mfma_f32_16x16x32_f16(Ah0, Bl0, acc, 0, 0, 0);
            acc = __builtin_amdgcn_mfma_f32_16x16x32_f16(Ah1, Bl1, acc, 0, 0, 0);
            acc = __builtin_amdgcn_mfma_f32_16x16x32_f16(Al0, Bh0, acc, 0, 0, 0);
            acc = __builtin_amdgcn_mfma_f32_16x16x32_f16(Al1, Bh1, acc, 0, 0, 0);
            acc = __builtin_amdgcn_mfma_f32_16x16x32_f16(Al0, Bl0, acc, 0, 0, 0);
            acc = __builtin_amdgcn_mfma_f32_16x16x32_f16(Al1, Bl1, acc, 0, 0, 0);
            float xnj = xn[bq * 512 + j];
            #pragma unroll
            for (int r = 0; r < 4; ++r)
                Sw[(quad * 4 + r) * 66 + js * 16 + lane16] = 2.f * acc[r] - xnj;
        }
        __syncthreads();
        // selection: lane scans its quarter's 16 columns of its row
        #pragma unroll
        for (int jj = 0; jj < 16; ++jj) {
            float v = Sw[lane16 * 66 + quad * 16 + jj];
            int j = jbase + quad * 16 + jj;
            if (v > kv[0]) {
                bool placed = false;
                #pragma unroll
                for (int q = 0; q < K; ++q) {
                    if (!placed) {
                        bool shift = (q + 1 < K) && (kv[q + 1] < v);
                        if (shift) { kv[q] = kv[q + 1]; kj[q] = kj[q + 1]; }
                        else { kv[q] = v; kj[q] = j; placed = true; }
                    }
                }
            }
        }
        __syncthreads();
    }
    // dump per-quarter lists, merge 4 sorted lists per row
    #pragma unroll
    for (int q = 0; q < K; ++q) {
        ldsMV[w][(lane16 * 4 + quad) * K + q] = kv[q];
        ldsMJ[w][(lane16 * 4 + quad) * K + q] = kj[q];
    }
    __syncthreads();
    if (quad == 0) {
        const float* MV = &ldsMV[w][lane16 * 4 * K];
        const int*   MJ = &ldsMJ[w][lane16 * 4 * K];
        int p0 = K - 1, p1 = K - 1, p2 = K - 1, p3 = K - 1;
        int* op = idx_out + ((size_t)bq * 512 + irow) * 16;
        for (int t = 0; t < K; ++t) {
            float bv = -3.4e38f; int bj = 0x7fffffff; int bc = -1;
            if (p0 >= 0) { float v = MV[p0]; int j = MJ[p0];
                if (v > bv || (v == bv && j < bj)) { bv = v; bj = j; bc = 0; } }
            if (p1 >= 0) { float v = MV[K + p1]; int j = MJ[K + p1];
                if (v > bv || (v == bv && j < bj)) { bv = v; bj = j; bc = 1; } }
            if (p2 >= 0) { float v = MV[2*K + p2]; int j = MJ[2*K + p2];
                if (v > bv || (v == bv && j < bj)) { bv = v; bj = j; bc = 2; } }
            if (p3 >= 0) { float v = MV[3*K + p3]; int j = MJ[3*K + p3];
                if (v > bv || (v == bv && j < bj)) { bv = v; bj = j; bc = 3; } }
            if (bc == 0) --p0; else if (bc == 1) --p1; else if (bc == 2) --p2; else --p3;
            op[t] = bj;
        }
    }
}

// ---------------- AB[bq] = [W1; W2-W1] (128x64) @ (X[bq] + vec) (64x512) ----------------
__global__ __launch_bounds__(256) void gemm_kernel(
    const float* __restrict__ X, const float* __restrict__ W,
    const float* __restrict__ vec, float* __restrict__ AB)
{
    __shared__ float ldsW[64 * 128];   // [c][o]
    __shared__ float ldsX[64 * 64];    // [c][i]
    int bq = blockIdx.x >> 3, itile = blockIdx.x & 7;
    int tid = threadIdx.x;
    const float* Xb = X + (size_t)bq * 32768;
    for (int p = 0; p < 32; ++p) {
        int t = p * 256 + tid;         // t = c*128 + o
        int c = t >> 7, o = t & 127;
        float val;
        if (o < 64) val = W[o * 128 + c];                                  // W1
        else        val = W[(o - 64) * 128 + 64 + c] - W[(o - 64) * 128 + c]; // W2-W1
        ldsW[t] = val;
    }
    int ibase = itile * 64;
    for (int p = 0; p < 16; ++p) {
        int t = p * 256 + tid;
        int c = t >> 6, il = t & 63;
        float v = Xb[c * 512 + ibase + il];
        if (vec) v += vec[bq * 64 + c];
        ldsX[t] = v;
    }
    __syncthreads();
    int tj = tid & 15, to = tid >> 4;
    int i0 = 4 * tj, o0 = 8 * to;
    float acc[8][4];
    #pragma unroll
    for (int a = 0; a < 8; ++a)
        #pragma unroll
        for (int b2 = 0; b2 < 4; ++b2) acc[a][b2] = 0.f;
    for (int c = 0; c < 64; ++c) {
        float4 xv  = *(float4*)&ldsX[c * 64 + i0];
        float4 w0v = *(float4*)&ldsW[c * 128 + o0];
        float4 w1v = *(float4*)&ldsW[c * 128 + o0 + 4];
        acc[0][0] += w0v.x * xv.x; acc[0][1] += w0v.x * xv.y; acc[0][2] += w0v.x * xv.z; acc[0][3] += w0v.x * xv.w;
        acc[1][0] += w0v.y * xv.x; acc[1][1] += w0v.y * xv.y; acc[1][2] += w0v.y * xv.z; acc[1][3] += w0v.y * xv.w;
        acc[2][0] += w0v.z * xv.x; acc[2][1] += w0v.z * xv.y; acc[2][2] += w0v.z * xv.z; acc[2][3] += w0v.z * xv.w;
        acc[3][0] += w0v.w * xv.x; acc[3][1] += w0v.w * xv.y; acc[3][2] += w0v.w * xv.z; acc[3][3] += w0v.w * xv.w;
        acc[4][0] += w1v.x * xv.x; acc[4][1] += w1v.x * xv.y; acc[4][2] += w1v.x * xv.z; acc[4][3] += w1v.x * xv.w;
        acc[5][0] += w1v.y * xv.x; acc[5][1] += w1v.y * xv.y; acc[5][2] += w1v.y * xv.z; acc[5][3] += w1v.y * xv.w;
        acc[6][0] += w1v.z * xv.x; acc[6][1] += w1v.z * xv.y; acc[6][2] += w1v.z * xv.z; acc[6][3] += w1v.z * xv.w;
        acc[7][0] += w1v.w * xv.x; acc[7][1] += w1v.w * xv.y; acc[7][2] += w1v.w * xv.z; acc[7][3] += w1v.w * xv.w;
    }
    float* out = AB + (size_t)bq * 65536 + ibase + i0;
    #pragma unroll
    for (int a = 0; a < 8; ++a) {
        float4 sv; sv.x = acc[a][0]; sv.y = acc[a][1]; sv.z = acc[a][2]; sv.w = acc[a][3];
        *(float4*)(out + (size_t)(o0 + a) * 512) = sv;
    }
}

// ---------------- branch epilogue ----------------
template<int ACC>
__global__ __launch_bounds__(256) void branch_reduce_kernel(
    const float* __restrict__ AB, const int* __restrict__ idx,
    const float* __restrict__ g, const float* __restrict__ bb,
    const float* __restrict__ mm, const float* __restrict__ vv,
    float* __restrict__ out_p, float* __restrict__ vec_out)
{
    __shared__ float ldsA[512];
    __shared__ int ldsIdx[512 * 10];
    __shared__ float ldsRed[8];
    __shared__ float sS[64], sT[64];
    int bq = blockIdx.x, tid = threadIdx.x;
    for (int p = 0; p < 20; ++p) {
        int t = p * 256 + tid;
        int i = t / 10, q = t - i * 10;
        ldsIdx[t] = idx[((size_t)bq * 512 + i) * 16 + q];
    }
    if (tid < 64) {
        float sc = g[tid] / sqrtf(vv[tid] + EPS);
        sS[tid] = sc;
        sT[tid] = bb[tid] - mm[tid] * sc;
    }
    __syncthreads();
    const float* ABb = AB + (size_t)bq * 65536;
    for (int o = 0; o < 64; ++o) {
        const float* Arow = ABb + o * 512;
        ldsA[tid] = Arow[tid];
        ldsA[tid + 256] = Arow[tid + 256];
        __syncthreads();
        const float* Brow = ABb + (64 + o) * 512;
        float s = sS[o], tsh = sT[o];
        float mymax = -3.4e38f, mysum = 0.f;
        for (int ii = tid; ii < 512; ii += 256) {
            const int* ip = &ldsIdx[ii * 10];
            float mx = ldsA[ip[0]];
            #pragma unroll
            for (int q = 1; q < 10; ++q) mx = fmaxf(mx, ldsA[ip[q]]);
            float val = (mx + Brow[ii]) * s + tsh;
            float y = val > 0.f ? val : 0.2f * val;
            mymax = fmaxf(mymax, y);
            mysum += y;
        }
        #pragma unroll
        for (int off = 32; off >= 1; off >>= 1) {
            mymax = fmaxf(mymax, __shfl_down(mymax, off));
            mysum += __shfl_down(mysum, off);
        }
        __syncthreads();
        int wv = tid >> 6, ln = tid & 63;
        if (ln == 0) { ldsRed[wv] = mymax; ldsRed[4 + wv] = mysum; }
        __syncthreads();
        if (tid == 0) {
            float M = fmaxf(fmaxf(ldsRed[0], ldsRed[1]), fmaxf(ldsRed[2], ldsRed[3]));
            float S = ldsRed[4] + ldsRed[5] + ldsRed[6] + ldsRed[7];
            float* po = out_p + bq * 128;
            if (ACC) {
                po[o] += M;
                po[64 + o] += S * (1.f / 512.f);
            } else {
                po[o] = M;
                po[64 + o] = S * (1.f / 512.f);
                vec_out[bq * 64 + o] = M;
            }
        }
    }
}

// ---------------- corre_binar: f, masks ----------------
__global__ __launch_bounds__(256) void corre_kernel(
    const float* __restrict__ x, const float* __restrict__ x0vec,
    const float* __restrict__ w_reduce, const int* __restrict__ idx8,
    float* __restrict__ fbuf, float* __restrict__ masks)
{
    __shared__ float sxv[64], sq[64], ss[512], sfk[512];
    int bq = blockIdx.x, tid = threadIdx.x;
    int row = src_row(bq);
    const float* Xb = x + (size_t)row * 32768;
    if (tid < 64) sxv[tid] = x0vec[bq * 64 + tid];
    __syncthreads();
    if (tid < 64) {
        float a = 0.f;
        for (int c = 0; c < 64; ++c) a += w_reduce[tid * 64 + c] * sxv[c];
        sq[tid] = a;
    }
    __syncthreads();
    for (int i = tid; i < 512; i += 256) {
        float a = 0.f;
        for (int c = 0; c < 64; ++c) a += sq[c] * Xb[c * 512 + i];
        a *= 0.125f;                    // 1/sqrt(64)
        ss[i] = a;
        fbuf[bq * 512 + i] = a;
    }
    __syncthreads();
    for (int i = tid; i < 512; i += 256) {
        float a = ss[i];
        const int* ip = idx8 + ((size_t)bq * 512 + i) * 16;
        for (int q = 0; q < 8; ++q) a += ss[ip[q]];
        sfk[i] = a;
    }
    masks[bq * 512 + tid] = 1.0f;
    masks[bq * 512 + tid + 256] = 1.0f;
    __syncthreads();
    if (tid == 0) {
        float best = sfk[0]; int bi = 0;
        for (int i = 1; i < 512; ++i) if (sfk[i] > best) { best = sfk[i]; bi = i; }
        masks[bq * 512 + bi] = 0.f;
        const int* ip = idx8 + ((size_t)bq * 512 + bi) * 16;
        for (int q = 0; q < 8; ++q) masks[bq * 512 + ip[q]] = 0.f;
    }
}

// ---------------- erase1 ----------------
__global__ __launch_bounds__(256) void erase1_kernel(
    const float* __restrict__ x, const float* __restrict__ masks,
    const float* __restrict__ fbuf,
    const float* __restrict__ w_e, const float* __restrict__ b_e,
    const float* __restrict__ g_e, const float* __restrict__ be_e,
    const float* __restrict__ m_e, const float* __restrict__ v_e,
    float* __restrict__ x1e)
{
    __shared__ float sw[512];
    __shared__ float smk[512];
    __shared__ float red[256];
    __shared__ float sres[64];
    __shared__ float sy[64];
    int bq = blockIdx.x, tid = threadIdx.x;
    int row = src_row(bq);
    const float* Xb = x + (size_t)row * 32768;
    float f0 = fbuf[bq * 512 + tid], f1 = fbuf[bq * 512 + tid + 256];
    float mk0 = masks[bq * 512 + tid], mk1 = masks[bq * 512 + tid + 256];
    smk[tid] = mk0; smk[tid + 256] = mk1;
    float s0 = f0 - (1.f - mk0) * 1e8f, s1 = f1 - (1.f - mk1) * 1e8f;
    red[tid] = fmaxf(s0, s1);
    __syncthreads();
    for (int off = 128; off >= 1; off >>= 1) {
        if (tid < off) red[tid] = fmaxf(red[tid], red[tid + off]);
        __syncthreads();
    }
    float mx = red[0];
    __syncthreads();
    float e0 = expf(s0 - mx), e1 = expf(s1 - mx);
    red[tid] = e0 + e1;
    __syncthreads();
    for (int off = 128; off >= 1; off >>= 1) {
        if (tid < off) red[tid] = red[tid] + red[tid + off];
        __syncthreads();
    }
    float inv = 1.f / red[0];
    __syncthreads();
    sw[tid] = e0 * inv; sw[tid + 256] = e1 * inv;
    __syncthreads();
    int c = tid >> 2, p = tid & 3;
    {
        float a = 0.f;
        const float* xr = Xb + c * 512 + p * 128;
        const float* wr = &sw[p * 128];
        for (int ii = 0; ii < 128; ++ii) a += xr[ii] * wr[ii];
        red[tid] = a;
    }
    __syncthreads();
    if (p == 0) sres[c] = red[tid] + red[tid + 1] + red[tid + 2] + red[tid + 3];
    __syncthreads();
    if (tid < 64) {
        float a = b_e[tid];
        for (int cc = 0; cc < 64; ++cc) a += w_e[tid * 64 + cc] * sres[cc];
        float sc = g_e[tid] / sqrtf(v_e[tid] + EPS);
        sy[tid] = (a - m_e[tid]) * sc + be_e[tid];
    }
    __syncthreads();
    float* ob = x1e + (size_t)bq * 32768;
    for (int p2 = 0; p2 < 128; ++p2) {
        int e = p2 * 256 + tid;
        int cc = e >> 9, i = e & 511;
        ob[e] = Xb[e] * smk[i] + sy[cc];
    }
}

extern "C" void kernel_launch(void* const* d_in, const int* in_sizes, int n_in,
                              void* d_out, int out_size, void* d_ws, size_t ws_size,
                              hipStream_t stream)
{
    const float* x        = (const float*)d_in[0];
    const float* w_reduce = (const float*)d_in[1];
    const float* w_erase  = (const float*)d_in[2];
    const float* b_erase  = (const float*)d_in[3];
    const float* g_erase  = (const float*)d_in[4];
    const float* be_erase = (const float*)d_in[5];
    const float* m_erase  = (const float*)d_in[6];
    const float* v_erase  = (const float*)d_in[7];
    const float* w0 = (const float*)d_in[8];
    const float* g0 = (const float*)d_in[9];
    const float* b0 = (const float*)d_in[10];
    const float* m0 = (const float*)d_in[11];
    const float* v0 = (const float*)d_in[12];
    const float* w1 = (const float*)d_in[13];
    const float* g1 = (const float*)d_in[14];
    const float* b1 = (const float*)d_in[15];
    const float* m1 = (const float*)d_in[16];
    const float* v1 = (const float*)d_in[17];
    float* out = (float*)d_out;
    char* ws = (char*)d_ws;

    float* xbuf  = (float*)(ws);                 // 12.58 MB: x1e fp32 [c][n]
    float* AB    = (float*)(ws + 12582912);      // 25.17 MB: AB, overlaid with h/l
    _Float16* h  = (_Float16*)(ws + 12582912);   //   h: 6.29 MB (alive only when AB dead)
    _Float16* lo = (_Float16*)(ws + 18874368);   //   l: 6.29 MB
    int*   idxA  = (int*)(ws + 37748736);        // 3.15 MB: k=10 idx (stride 16)
    int*   idx8  = (int*)(ws + 40894464);        // 3.15 MB: k=8 idx
    float* xn    = (float*)(ws + 44040192);      // 192 KB: col norms
    float* y0vec = (float*)(ws + 44236800);      // 24 KB
    float* x0vec = (float*)(ws + 44261376);      // 24 KB
    float* fbuf  = (float*)(ws + 44285952);      // 192 KB
    float* masks = (float*)(ws + 44482560);      // 192 KB

    (void)in_sizes; (void)n_in; (void)out_size; (void)ws_size;

    // x0 = erase(x, ones, ones) = x + y0vec
    erase0_kernel<<<96, 256, 0, stream>>>(x, w_erase, b_erase, g_erase, be_erase, m_erase, v_erase, y0vec);
    // branch 0
    prep_kernel<<<768, 256, 0, stream>>>(x, y0vec, 0, h, lo, xn);
    knn_mfma_kernel<10><<<768, 256, 0, stream>>>(h, lo, xn, idxA);
    gemm_kernel<<<768, 256, 0, stream>>>(x, w0, y0vec, AB);
    branch_reduce_kernel<0><<<96, 256, 0, stream>>>(AB, idxA, g0, b0, m0, v0, out, x0vec);
    // corre_binar on x1seq (x with t-shift remap)
    prep_kernel<<<768, 256, 0, stream>>>(x, nullptr, 1, h, lo, xn);
    knn_mfma_kernel<8><<<768, 256, 0, stream>>>(h, lo, xn, idx8);
    corre_kernel<<<96, 256, 0, stream>>>(x, x0vec, w_reduce, idx8, fbuf, masks);
    // x1e = erase(x1seq, masks, f)
    erase1_kernel<<<96, 256, 0, stream>>>(x, masks, fbuf, w_erase, b_erase, g_erase, be_erase, m_erase, v_erase, xbuf);
    // branch 1
    prep_kernel<<<768, 256, 0, stream>>>(xbuf, nullptr, 0, h, lo, xn);
    knn_mfma_kernel<10><<<768, 256, 0, stream>>>(h, lo, xn, idxA);
    gemm_kernel<<<768, 256, 0, stream>>>(xbuf, w1, nullptr, AB);
    branch_reduce_kernel<1><<<96, 256, 0, stream>>>(AB, idxA, g1, b1, m1, v1, out, nullptr);
}

// Round 3
// 528.075 us; speedup vs baseline: 1.7653x; 1.3931x over previous
//
#include <hip/hip_runtime.h>
#include <math.h>

#define EPS 1e-5f

typedef _Float16 half8 __attribute__((ext_vector_type(8)));
typedef float f32x4 __attribute__((ext_vector_type(4)));

// bq in [0,96): b = bq/12, t = bq%12; x1seq row = b*12 + min(t+1, 11)
__device__ __forceinline__ int src_row(int bq) {
    int b = bq / 12, t = bq - b * 12;
    int t2 = (t + 1 < 12) ? (t + 1) : 11;
    return b * 12 + t2;
}

// ---------------- erase0: y0vec[bq][o] = BN(W_e @ mean_n(x) + b_e) ----------------
__global__ __launch_bounds__(256) void erase0_kernel(
    const float* __restrict__ x, const float* __restrict__ w_e,
    const float* __restrict__ b_e, const float* __restrict__ g_e,
    const float* __restrict__ be_e, const float* __restrict__ m_e,
    const float* __restrict__ v_e, float* __restrict__ y0vec)
{
    __shared__ float part[256];
    __shared__ float res[64];
    int bq = blockIdx.x, tid = threadIdx.x;
    int c = tid >> 2, p = tid & 3;
    const float* xb = x + (size_t)bq * 32768 + c * 512 + p * 128;
    float acc = 0.f;
    for (int ii = 0; ii < 128; ii += 4) {
        float4 v = *(const float4*)(xb + ii);
        acc += v.x + v.y + v.z + v.w;
    }
    part[tid] = acc;
    __syncthreads();
    if (p == 0) res[c] = (part[tid] + part[tid+1] + part[tid+2] + part[tid+3]) * (1.f/512.f);
    __syncthreads();
    if (tid < 64) {
        float a = b_e[tid];
        for (int cc = 0; cc < 64; ++cc) a += w_e[tid*64+cc] * res[cc];
        float s = g_e[tid] / sqrtf(v_e[tid] + EPS);
        y0vec[bq*64 + tid] = (a - m_e[tid]) * s + be_e[tid];
    }
}

// ---------------- prep: fp16 split (h,l) in [n][c] layout + exact fp32 colnorms ----------------
__global__ __launch_bounds__(256) void prep_kernel(
    const float* __restrict__ X, const float* __restrict__ vec, int remap,
    _Float16* __restrict__ H, _Float16* __restrict__ L, float* __restrict__ xn)
{
    __shared__ float lds[64 * 65];     // [c][col] pad
    __shared__ float xnp[4 * 64];
    int bq = blockIdx.x >> 3, ct = blockIdx.x & 7;
    int row = remap ? src_row(bq) : bq;
    const float* Xb = X + (size_t)row * 32768 + ct * 64;
    int tid = threadIdx.x;
    for (int p = 0; p < 16; ++p) {
        int t = p * 256 + tid;
        int c = t >> 6, col = t & 63;
        float v = Xb[c * 512 + col];
        if (vec) v += vec[bq * 64 + c];
        lds[c * 65 + col] = v;
    }
    __syncthreads();
    int col = tid & 63, g = tid >> 6;       // g: group of 16 channels
    half8 hv[2], lv[2];
    float s = 0.f;
    #pragma unroll
    for (int k = 0; k < 16; ++k) {
        int c = g * 16 + k;
        float v = lds[c * 65 + col];
        _Float16 h = (_Float16)v;
        _Float16 lo = (_Float16)(v - (float)h);
        hv[k >> 3][k & 7] = h;
        lv[k >> 3][k & 7] = lo;
        s += v * v;
    }
    size_t obase = ((size_t)bq * 512 + ct * 64 + col) * 64 + g * 16;
    *(half8*)(H + obase) = hv[0];
    *(half8*)(H + obase + 8) = hv[1];
    *(half8*)(L + obase) = lv[0];
    *(half8*)(L + obase + 8) = lv[1];
    xnp[g * 64 + col] = s;
    __syncthreads();
    if (tid < 64)
        xn[bq * 512 + ct * 64 + tid] =
            xnp[tid] + xnp[64 + tid] + xnp[128 + tid] + xnp[192 + tid];
}

// ---------------- kNN v2: transposed MFMA (D[j][i]); selection in registers ----------------
// Wave w owns i-rows itile*64+w*16+lane16; lane accumulates scores for its own row.
// score[j] = 2*dot(x_i,x_j) - xn[j]. No barriers in the hot loop.
template<int K>
__global__ __launch_bounds__(256) void knn_mfma_kernel(
    const _Float16* __restrict__ H, const _Float16* __restrict__ L,
    const float* __restrict__ xn, int* __restrict__ idx_out)
{
    __shared__ float ldsMV[4][16 * 4 * K];
    __shared__ int   ldsMJ[4][16 * 4 * K];
    int bq = blockIdx.x >> 3, itile = blockIdx.x & 7;
    int tid = threadIdx.x, w = tid >> 6, l = tid & 63;
    int lane16 = l & 15, quad = l >> 4;
    const size_t base = (size_t)bq * 512 * 64;
    int irow = itile * 64 + w * 16 + lane16;
    // B operand = this wave's i-rows (fixed in registers)
    const _Float16* Hi = H + base + (size_t)irow * 64 + quad * 8;
    const _Float16* Li = L + base + (size_t)irow * 64 + quad * 8;
    half8 Bh0 = *(const half8*)(Hi);
    half8 Bh1 = *(const half8*)(Hi + 32);
    half8 Bl0 = *(const half8*)(Li);
    half8 Bl1 = *(const half8*)(Li + 32);
    float kv[K]; int kj[K];
    #pragma unroll
    for (int q = 0; q < K; ++q) { kv[q] = -3.4e38f; kj[q] = 0; }
    auto ins = [&](float v, int j) {
        if (v > kv[0]) {            // strict >: earlier j wins ties (matches lax.top_k)
            bool placed = false;
            #pragma unroll
            for (int q = 0; q < K; ++q) {
                if (!placed) {
                    bool shift = (q + 1 < K) && (kv[q + 1] < v);
                    if (shift) { kv[q] = kv[q + 1]; kj[q] = kj[q + 1]; }
                    else { kv[q] = v; kj[q] = j; placed = true; }
                }
            }
        }
    };
    const float* xnb = xn + bq * 512;
    for (int jt = 0; jt < 8; ++jt) {
        #pragma unroll
        for (int g = 0; g < 4; ++g) {
            int jrow = jt * 64 + g * 16 + lane16;
            const _Float16* Hj = H + base + (size_t)jrow * 64 + quad * 8;
            const _Float16* Lj = L + base + (size_t)jrow * 64 + quad * 8;
            half8 Ah0 = *(const half8*)(Hj);
            half8 Ah1 = *(const half8*)(Hj + 32);
            half8 Al0 = *(const half8*)(Lj);
            half8 Al1 = *(const half8*)(Lj + 32);
            f32x4 acc = {0.f, 0.f, 0.f, 0.f};
            acc = __builtin_amdgcn_mfma_f32_16x16x32_f16(Ah0, Bh0, acc, 0, 0, 0);
            acc = __builtin_amdgcn_mfma_f32_16x16x32_f16(Ah1, Bh1, acc, 0, 0, 0);
            acc = __builtin_amdgcn_mfma_f32_16x16x32_f16(Al0, Bh0, acc, 0, 0, 0);
            acc = __builtin_amdgcn_mfma_f32_16x16x32_f16(Al1, Bh1, acc, 0, 0, 0);
            acc = __builtin_amdgcn_mfma_f32_16x16x32_f16(Ah0, Bl0, acc, 0, 0, 0);
            acc = __builtin_amdgcn_mfma_f32_16x16x32_f16(Ah1, Bl1, acc, 0, 0, 0);
            // (L*L term dropped: ~3e-7, below fp32 accumulation noise)
            int jb = jt * 64 + g * 16 + quad * 4;   // lane holds rows jb..jb+3, col = irow
            float4 xn4 = *(const float4*)&xnb[jb];
            float s0 = 2.f * acc[0] - xn4.x;
            float s1 = 2.f * acc[1] - xn4.y;
            float s2 = 2.f * acc[2] - xn4.z;
            float s3 = 2.f * acc[3] - xn4.w;
            float m4 = fmaxf(fmaxf(s0, s1), fmaxf(s2, s3));
            if (m4 > kv[0]) {
                ins(s0, jb + 0); ins(s1, jb + 1); ins(s2, jb + 2); ins(s3, jb + 3);
            }
        }
    }
    // dump per-quad lists, merge 4 sorted lists per row
    #pragma unroll
    for (int q = 0; q < K; ++q) {
        ldsMV[w][(lane16 * 4 + quad) * K + q] = kv[q];
        ldsMJ[w][(lane16 * 4 + quad) * K + q] = kj[q];
    }
    __syncthreads();
    if (quad == 0) {
        const float* MV = &ldsMV[w][lane16 * 4 * K];
        const int*   MJ = &ldsMJ[w][lane16 * 4 * K];
        int p0 = K - 1, p1 = K - 1, p2 = K - 1, p3 = K - 1;
        int* op = idx_out + ((size_t)bq * 512 + irow) * 16;
        for (int t = 0; t < K; ++t) {
            float bv = -3.4e38f; int bj = 0x7fffffff; int bc = -1;
            if (p0 >= 0) { float v = MV[p0]; int j = MJ[p0];
                if (v > bv || (v == bv && j < bj)) { bv = v; bj = j; bc = 0; } }
            if (p1 >= 0) { float v = MV[K + p1]; int j = MJ[K + p1];
                if (v > bv || (v == bv && j < bj)) { bv = v; bj = j; bc = 1; } }
            if (p2 >= 0) { float v = MV[2*K + p2]; int j = MJ[2*K + p2];
                if (v > bv || (v == bv && j < bj)) { bv = v; bj = j; bc = 2; } }
            if (p3 >= 0) { float v = MV[3*K + p3]; int j = MJ[3*K + p3];
                if (v > bv || (v == bv && j < bj)) { bv = v; bj = j; bc = 3; } }
            if (bc == 0) --p0; else if (bc == 1) --p1; else if (bc == 2) --p2; else --p3;
            op[t] = bj;
        }
    }
}

// ---------------- AB[bq] = [W1; W2-W1] (128x64) @ (X[bq] + vec) (64x512) ----------------
__global__ __launch_bounds__(256) void gemm_kernel(
    const float* __restrict__ X, const float* __restrict__ W,
    const float* __restrict__ vec, float* __restrict__ AB)
{
    __shared__ float ldsW[64 * 128];   // [c][o]
    __shared__ float ldsX[64 * 64];    // [c][i]
    int bq = blockIdx.x >> 3, itile = blockIdx.x & 7;
    int tid = threadIdx.x;
    const float* Xb = X + (size_t)bq * 32768;
    for (int p = 0; p < 32; ++p) {
        int t = p * 256 + tid;         // t = c*128 + o
        int c = t >> 7, o = t & 127;
        float val;
        if (o < 64) val = W[o * 128 + c];                                  // W1
        else        val = W[(o - 64) * 128 + 64 + c] - W[(o - 64) * 128 + c]; // W2-W1
        ldsW[t] = val;
    }
    int ibase = itile * 64;
    for (int p = 0; p < 16; ++p) {
        int t = p * 256 + tid;
        int c = t >> 6, il = t & 63;
        float v = Xb[c * 512 + ibase + il];
        if (vec) v += vec[bq * 64 + c];
        ldsX[t] = v;
    }
    __syncthreads();
    int tj = tid & 15, to = tid >> 4;
    int i0 = 4 * tj, o0 = 8 * to;
    float acc[8][4];
    #pragma unroll
    for (int a = 0; a < 8; ++a)
        #pragma unroll
        for (int b2 = 0; b2 < 4; ++b2) acc[a][b2] = 0.f;
    for (int c = 0; c < 64; ++c) {
        float4 xv  = *(float4*)&ldsX[c * 64 + i0];
        float4 w0v = *(float4*)&ldsW[c * 128 + o0];
        float4 w1v = *(float4*)&ldsW[c * 128 + o0 + 4];
        acc[0][0] += w0v.x * xv.x; acc[0][1] += w0v.x * xv.y; acc[0][2] += w0v.x * xv.z; acc[0][3] += w0v.x * xv.w;
        acc[1][0] += w0v.y * xv.x; acc[1][1] += w0v.y * xv.y; acc[1][2] += w0v.y * xv.z; acc[1][3] += w0v.y * xv.w;
        acc[2][0] += w0v.z * xv.x; acc[2][1] += w0v.z * xv.y; acc[2][2] += w0v.z * xv.z; acc[2][3] += w0v.z * xv.w;
        acc[3][0] += w0v.w * xv.x; acc[3][1] += w0v.w * xv.y; acc[3][2] += w0v.w * xv.z; acc[3][3] += w0v.w * xv.w;
        acc[4][0] += w1v.x * xv.x; acc[4][1] += w1v.x * xv.y; acc[4][2] += w1v.x * xv.z; acc[4][3] += w1v.x * xv.w;
        acc[5][0] += w1v.y * xv.x; acc[5][1] += w1v.y * xv.y; acc[5][2] += w1v.y * xv.z; acc[5][3] += w1v.y * xv.w;
        acc[6][0] += w1v.z * xv.x; acc[6][1] += w1v.z * xv.y; acc[6][2] += w1v.z * xv.z; acc[6][3] += w1v.z * xv.w;
        acc[7][0] += w1v.w * xv.x; acc[7][1] += w1v.w * xv.y; acc[7][2] += w1v.w * xv.z; acc[7][3] += w1v.w * xv.w;
    }
    float* out = AB + (size_t)bq * 65536 + ibase + i0;
    #pragma unroll
    for (int a = 0; a < 8; ++a) {
        float4 sv; sv.x = acc[a][0]; sv.y = acc[a][1]; sv.z = acc[a][2]; sv.w = acc[a][3];
        *(float4*)(out + (size_t)(o0 + a) * 512) = sv;
    }
}

// ---------------- branch epilogue v2: wave-parallel over o, 3 barriers total ----------------
// y[o,i] = lrelu(s_o*(max_k A[o,idx[i,k]] + B[o,i]) + t_o); p[o]=max_i, p[64+o]=mean_i.
template<int ACC>
__global__ __launch_bounds__(256) void branch_reduce_kernel(
    const float* __restrict__ AB, const int* __restrict__ idx,
    const float* __restrict__ g, const float* __restrict__ bb,
    const float* __restrict__ mm, const float* __restrict__ vv,
    float* __restrict__ out_p, float* __restrict__ vec_out)
{
    __shared__ float ldsA[32 * 512];       // 64 KB: A-chunk [o][i]
    __shared__ int   ldsIdx[512 * 10];     // 20 KB
    __shared__ float sS[64], sT[64];
    int bq = blockIdx.x, tid = threadIdx.x;
    int w = tid >> 6, ln = tid & 63;
    for (int p = 0; p < 20; ++p) {
        int t = p * 256 + tid;
        int i = t / 10, q = t - i * 10;
        ldsIdx[t] = idx[((size_t)bq * 512 + i) * 16 + q];
    }
    if (tid < 64) {
        float sc = g[tid] / sqrtf(vv[tid] + EPS);
        sS[tid] = sc;
        sT[tid] = bb[tid] - mm[tid] * sc;
    }
    const float* ABb = AB + (size_t)bq * 65536;
    for (int chunk = 0; chunk < 2; ++chunk) {
        __syncthreads();                   // idx/sS ready (c0); ldsA free (c1)
        int ob = chunk * 32;
        for (int p = 0; p < 16; ++p) {
            int t = p * 256 + tid;         // float4 index into 32*512
            int o = t >> 7, i4 = t & 127;
            *(float4*)&ldsA[o * 512 + i4 * 4] = *(const float4*)&ABb[(size_t)(ob + o) * 512 + i4 * 4];
        }
        __syncthreads();
        float ssr[8], str[8];
        #pragma unroll
        for (int oo = 0; oo < 8; ++oo) {
            int o = ob + w * 8 + oo;
            ssr[oo] = sS[o]; str[oo] = sT[o];
        }
        float omax[8], osum[8];
        #pragma unroll
        for (int oo = 0; oo < 8; ++oo) { omax[oo] = -3.4e38f; osum[oo] = 0.f; }
        const float* Aw = ldsA + (w * 8) * 512;
        for (int s = 0; s < 8; ++s) {
            int i = ln + 64 * s;
            int idr[10];
            const int* ip = &ldsIdx[i * 10];
            #pragma unroll
            for (int q = 0; q < 10; ++q) idr[q] = ip[q];
            #pragma unroll
            for (int oo = 0; oo < 8; ++oo) {
                const float* Ao = Aw + oo * 512;
                float mx = Ao[idr[0]];
                #pragma unroll
                for (int q = 1; q < 10; ++q) mx = fmaxf(mx, Ao[idr[q]]);
                float Bv = ABb[(size_t)(64 + ob + w * 8 + oo) * 512 + i];
                float val = (mx + Bv) * ssr[oo] + str[oo];
                float y = val > 0.f ? val : 0.2f * val;
                omax[oo] = fmaxf(omax[oo], y);
                osum[oo] += y;
            }
        }
        #pragma unroll
        for (int oo = 0; oo < 8; ++oo) {
            float M = omax[oo], S = osum[oo];
            #pragma unroll
            for (int off = 32; off >= 1; off >>= 1) {
                M = fmaxf(M, __shfl_down(M, off));
                S += __shfl_down(S, off);
            }
            if (ln == 0) {
                int o = ob + w * 8 + oo;
                float* po = out_p + bq * 128;
                if (ACC) {
                    po[o] += M;
                    po[64 + o] += S * (1.f / 512.f);
                } else {
                    po[o] = M;
                    po[64 + o] = S * (1.f / 512.f);
                    vec_out[bq * 64 + o] = M;
                }
            }
        }
    }
}

// ---------------- corre_binar: f, masks ----------------
__global__ __launch_bounds__(256) void corre_kernel(
    const float* __restrict__ x, const float* __restrict__ x0vec,
    const float* __restrict__ w_reduce, const int* __restrict__ idx8,
    float* __restrict__ fbuf, float* __restrict__ masks)
{
    __shared__ float sxv[64], sq[64], ss[512], sfk[512];
    int bq = blockIdx.x, tid = threadIdx.x;
    int row = src_row(bq);
    const float* Xb = x + (size_t)row * 32768;
    if (tid < 64) sxv[tid] = x0vec[bq * 64 + tid];
    __syncthreads();
    if (tid < 64) {
        float a = 0.f;
        for (int c = 0; c < 64; ++c) a += w_reduce[tid * 64 + c] * sxv[c];
        sq[tid] = a;
    }
    __syncthreads();
    for (int i = tid; i < 512; i += 256) {
        float a = 0.f;
        for (int c = 0; c < 64; ++c) a += sq[c] * Xb[c * 512 + i];
        a *= 0.125f;                    // 1/sqrt(64)
        ss[i] = a;
        fbuf[bq * 512 + i] = a;
    }
    __syncthreads();
    for (int i = tid; i < 512; i += 256) {
        float a = ss[i];
        const int* ip = idx8 + ((size_t)bq * 512 + i) * 16;
        for (int q = 0; q < 8; ++q) a += ss[ip[q]];
        sfk[i] = a;
    }
    masks[bq * 512 + tid] = 1.0f;
    masks[bq * 512 + tid + 256] = 1.0f;
    __syncthreads();
    if (tid == 0) {
        float best = sfk[0]; int bi = 0;
        for (int i = 1; i < 512; ++i) if (sfk[i] > best) { best = sfk[i]; bi = i; }
        masks[bq * 512 + bi] = 0.f;
        const int* ip = idx8 + ((size_t)bq * 512 + bi) * 16;
        for (int q = 0; q < 8; ++q) masks[bq * 512 + ip[q]] = 0.f;
    }
}

// ---------------- erase1 ----------------
__global__ __launch_bounds__(256) void erase1_kernel(
    const float* __restrict__ x, const float* __restrict__ masks,
    const float* __restrict__ fbuf,
    const float* __restrict__ w_e, const float* __restrict__ b_e,
    const float* __restrict__ g_e, const float* __restrict__ be_e,
    const float* __restrict__ m_e, const float* __restrict__ v_e,
    float* __restrict__ x1e)
{
    __shared__ float sw[512];
    __shared__ float smk[512];
    __shared__ float red[256];
    __shared__ float sres[64];
    __shared__ float sy[64];
    int bq = blockIdx.x, tid = threadIdx.x;
    int row = src_row(bq);
    const float* Xb = x + (size_t)row * 32768;
    float f0 = fbuf[bq * 512 + tid], f1 = fbuf[bq * 512 + tid + 256];
    float mk0 = masks[bq * 512 + tid], mk1 = masks[bq * 512 + tid + 256];
    smk[tid] = mk0; smk[tid + 256] = mk1;
    float s0 = f0 - (1.f - mk0) * 1e8f, s1 = f1 - (1.f - mk1) * 1e8f;
    red[tid] = fmaxf(s0, s1);
    __syncthreads();
    for (int off = 128; off >= 1; off >>= 1) {
        if (tid < off) red[tid] = fmaxf(red[tid], red[tid + off]);
        __syncthreads();
    }
    float mx = red[0];
    __syncthreads();
    float e0 = expf(s0 - mx), e1 = expf(s1 - mx);
    red[tid] = e0 + e1;
    __syncthreads();
    for (int off = 128; off >= 1; off >>= 1) {
        if (tid < off) red[tid] = red[tid] + red[tid + off];
        __syncthreads();
    }
    float inv = 1.f / red[0];
    __syncthreads();
    sw[tid] = e0 * inv; sw[tid + 256] = e1 * inv;
    __syncthreads();
    int c = tid >> 2, p = tid & 3;
    {
        float a = 0.f;
        const float* xr = Xb + c * 512 + p * 128;
        const float* wr = &sw[p * 128];
        for (int ii = 0; ii < 128; ++ii) a += xr[ii] * wr[ii];
        red[tid] = a;
    }
    __syncthreads();
    if (p == 0) sres[c] = red[tid] + red[tid + 1] + red[tid + 2] + red[tid + 3];
    __syncthreads();
    if (tid < 64) {
        float a = b_e[tid];
        for (int cc = 0; cc < 64; ++cc) a += w_e[tid * 64 + cc] * sres[cc];
        float sc = g_e[tid] / sqrtf(v_e[tid] + EPS);
        sy[tid] = (a - m_e[tid]) * sc + be_e[tid];
    }
    __syncthreads();
    float* ob = x1e + (size_t)bq * 32768;
    for (int p2 = 0; p2 < 128; ++p2) {
        int e = p2 * 256 + tid;
        int cc = e >> 9, i = e & 511;
        ob[e] = Xb[e] * smk[i] + sy[cc];
    }
}

extern "C" void kernel_launch(void* const* d_in, const int* in_sizes, int n_in,
                              void* d_out, int out_size, void* d_ws, size_t ws_size,
                              hipStream_t stream)
{
    const float* x        = (const float*)d_in[0];
    const float* w_reduce = (const float*)d_in[1];
    const float* w_erase  = (const float*)d_in[2];
    const float* b_erase  = (const float*)d_in[3];
    const float* g_erase  = (const float*)d_in[4];
    const float* be_erase = (const float*)d_in[5];
    const float* m_erase  = (const float*)d_in[6];
    const float* v_erase  = (const float*)d_in[7];
    const float* w0 = (const float*)d_in[8];
    const float* g0 = (const float*)d_in[9];
    const float* b0 = (const float*)d_in[10];
    const float* m0 = (const float*)d_in[11];
    const float* v0 = (const float*)d_in[12];
    const float* w1 = (const float*)d_in[13];
    const float* g1 = (const float*)d_in[14];
    const float* b1 = (const float*)d_in[15];
    const float* m1 = (const float*)d_in[16];
    const float* v1 = (const float*)d_in[17];
    float* out = (float*)d_out;
    char* ws = (char*)d_ws;

    float* xbuf  = (float*)(ws);                 // 12.58 MB: x1e fp32 [c][n]
    float* AB    = (float*)(ws + 12582912);      // 25.17 MB: AB, overlaid with h/l
    _Float16* h  = (_Float16*)(ws + 12582912);   //   h: 6.29 MB (alive only when AB dead)
    _Float16* lo = (_Float16*)(ws + 18874368);   //   l: 6.29 MB
    int*   idxA  = (int*)(ws + 37748736);        // 3.15 MB: k=10 idx (stride 16)
    int*   idx8  = (int*)(ws + 40894464);        // 3.15 MB: k=8 idx
    float* xn    = (float*)(ws + 44040192);      // 192 KB: col norms
    float* y0vec = (float*)(ws + 44236800);      // 24 KB
    float* x0vec = (float*)(ws + 44261376);      // 24 KB
    float* fbuf  = (float*)(ws + 44285952);      // 192 KB
    float* masks = (float*)(ws + 44482560);      // 192 KB

    (void)in_sizes; (void)n_in; (void)out_size; (void)ws_size;

    // x0 = erase(x, ones, ones) = x + y0vec
    erase0_kernel<<<96, 256, 0, stream>>>(x, w_erase, b_erase, g_erase, be_erase, m_erase, v_erase, y0vec);
    // branch 0
    prep_kernel<<<768, 256, 0, stream>>>(x, y0vec, 0, h, lo, xn);
    knn_mfma_kernel<10><<<768, 256, 0, stream>>>(h, lo, xn, idxA);
    gemm_kernel<<<768, 256, 0, stream>>>(x, w0, y0vec, AB);
    branch_reduce_kernel<0><<<96, 256, 0, stream>>>(AB, idxA, g0, b0, m0, v0, out, x0vec);
    // corre_binar on x1seq (x with t-shift remap)
    prep_kernel<<<768, 256, 0, stream>>>(x, nullptr, 1, h, lo, xn);
    knn_mfma_kernel<8><<<768, 256, 0, stream>>>(h, lo, xn, idx8);
    corre_kernel<<<96, 256, 0, stream>>>(x, x0vec, w_reduce, idx8, fbuf, masks);
    // x1e = erase(x1seq, masks, f)
    erase1_kernel<<<96, 256, 0, stream>>>(x, masks, fbuf, w_erase, b_erase, g_erase, be_erase, m_erase, v_erase, xbuf);
    // branch 1
    prep_kernel<<<768, 256, 0, stream>>>(xbuf, nullptr, 0, h, lo, xn);
    knn_mfma_kernel<10><<<768, 256, 0, stream>>>(h, lo, xn, idxA);
    gemm_kernel<<<768, 256, 0, stream>>>(xbuf, w1, nullptr, AB);
    branch_reduce_kernel<1><<<96, 256, 0, stream>>>(AB, idxA, g1, b1, m1, v1, out, nullptr);
}

// Round 4
// 497.692 us; speedup vs baseline: 1.8731x; 1.0610x over previous
//
#include <hip/hip_runtime.h>
#include <math.h>

#define EPS 1e-5f

typedef _Float16 half8 __attribute__((ext_vector_type(8)));
typedef float f32x4 __attribute__((ext_vector_type(4)));

// bq in [0,96): b = bq/12, t = bq%12; x1seq row = b*12 + min(t+1, 11)
__device__ __forceinline__ int src_row(int bq) {
    int b = bq / 12, t = bq - b * 12;
    int t2 = (t + 1 < 12) ? (t + 1) : 11;
    return b * 12 + t2;
}

// ---------------- erase0: y0vec[bq][o] = BN(W_e @ mean_n(x) + b_e) ----------------
__global__ __launch_bounds__(256) void erase0_kernel(
    const float* __restrict__ x, const float* __restrict__ w_e,
    const float* __restrict__ b_e, const float* __restrict__ g_e,
    const float* __restrict__ be_e, const float* __restrict__ m_e,
    const float* __restrict__ v_e, float* __restrict__ y0vec)
{
    __shared__ float part[256];
    __shared__ float res[64];
    int bq = blockIdx.x, tid = threadIdx.x;
    int c = tid >> 2, p = tid & 3;
    const float* xb = x + (size_t)bq * 32768 + c * 512 + p * 128;
    float acc = 0.f;
    for (int ii = 0; ii < 128; ii += 4) {
        float4 v = *(const float4*)(xb + ii);
        acc += v.x + v.y + v.z + v.w;
    }
    part[tid] = acc;
    __syncthreads();
    if (p == 0) res[c] = (part[tid] + part[tid+1] + part[tid+2] + part[tid+3]) * (1.f/512.f);
    __syncthreads();
    if (tid < 64) {
        float a = b_e[tid];
        for (int cc = 0; cc < 64; ++cc) a += w_e[tid*64+cc] * res[cc];
        float s = g_e[tid] / sqrtf(v_e[tid] + EPS);
        y0vec[bq*64 + tid] = (a - m_e[tid]) * s + be_e[tid];
    }
}

// ---------------- prep: fp16 split (h,l) in [n][c] layout + exact fp32 colnorms ----------------
__global__ __launch_bounds__(256) void prep_kernel(
    const float* __restrict__ X, const float* __restrict__ vec, int remap,
    _Float16* __restrict__ H, _Float16* __restrict__ L, float* __restrict__ xn)
{
    __shared__ float lds[64 * 65];     // [c][col] pad
    __shared__ float xnp[4 * 64];
    int bq = blockIdx.x >> 3, ct = blockIdx.x & 7;
    int row = remap ? src_row(bq) : bq;
    const float* Xb = X + (size_t)row * 32768 + ct * 64;
    int tid = threadIdx.x;
    for (int p = 0; p < 16; ++p) {
        int t = p * 256 + tid;
        int c = t >> 6, col = t & 63;
        float v = Xb[c * 512 + col];
        if (vec) v += vec[bq * 64 + c];
        lds[c * 65 + col] = v;
    }
    __syncthreads();
    int col = tid & 63, g = tid >> 6;       // g: group of 16 channels
    half8 hv[2], lv[2];
    float s = 0.f;
    #pragma unroll
    for (int k = 0; k < 16; ++k) {
        int c = g * 16 + k;
        float v = lds[c * 65 + col];
        _Float16 h = (_Float16)v;
        _Float16 lo = (_Float16)(v - (float)h);
        hv[k >> 3][k & 7] = h;
        lv[k >> 3][k & 7] = lo;
        s += v * v;
    }
    size_t obase = ((size_t)bq * 512 + ct * 64 + col) * 64 + g * 16;
    *(half8*)(H + obase) = hv[0];
    *(half8*)(H + obase + 8) = hv[1];
    *(half8*)(L + obase) = lv[0];
    *(half8*)(L + obase + 8) = lv[1];
    xnp[g * 64 + col] = s;
    __syncthreads();
    if (tid < 64)
        xn[bq * 512 + ct * 64 + tid] =
            xnp[tid] + xnp[64 + tid] + xnp[128 + tid] + xnp[192 + tid];
}

// ---------------- kNN v3: transposed MFMA + bitonic sort-16 selection ----------------
// Wave w owns i-rows itile*64+w*16+lane16; lane holds scores for its own row.
// Per jt: 16 scores -> bitonic sort-16 -> exact top-16 merge with running list.
// Selection is data-independent (no wave-divergent insert chains).
template<int K>
__global__ __launch_bounds__(256) void knn_mfma_kernel(
    const _Float16* __restrict__ H, const _Float16* __restrict__ L,
    const float* __restrict__ xn, int* __restrict__ idx_out)
{
    __shared__ float ldsMV[4][16 * 64];   // per wave: 16 rows x 4 quads x 16 vals (asc)
    __shared__ int   ldsMJ[4][16 * 64];
    int bq = blockIdx.x >> 3, itile = blockIdx.x & 7;
    int tid = threadIdx.x, w = tid >> 6, l = tid & 63;
    int lane16 = l & 15, quad = l >> 4;
    const size_t base = (size_t)bq * 512 * 64;
    int irow = itile * 64 + w * 16 + lane16;
    // B operand = this wave's i-rows (fixed in registers)
    const _Float16* Hi = H + base + (size_t)irow * 64 + quad * 8;
    const _Float16* Li = L + base + (size_t)irow * 64 + quad * 8;
    half8 Bh0 = *(const half8*)(Hi);
    half8 Bh1 = *(const half8*)(Hi + 32);
    half8 Bl0 = *(const half8*)(Li);
    half8 Bl1 = *(const half8*)(Li + 32);

    float kv[16]; int kj[16];              // running top-16, ascending (kv[15]=best)
    #pragma unroll
    for (int q = 0; q < 16; ++q) { kv[q] = -3.4e38f; kj[q] = 0; }

    auto cas_asc = [](float& va, int& ja, float& vb, int& jb2) {
        bool sw = va > vb;
        float tv = va; int tj = ja;
        va = sw ? vb : va; ja = sw ? jb2 : ja;
        vb = sw ? tv : vb; jb2 = sw ? tj : jb2;
    };

    const float* xnb = xn + bq * 512;
    for (int jt = 0; jt < 8; ++jt) {
        float d[16]; int jd[16];
        #pragma unroll
        for (int g = 0; g < 4; ++g) {
            int jrow = jt * 64 + g * 16 + lane16;
            const _Float16* Hj = H + base + (size_t)jrow * 64 + quad * 8;
            const _Float16* Lj = L + base + (size_t)jrow * 64 + quad * 8;
            half8 Ah0 = *(const half8*)(Hj);
            half8 Ah1 = *(const half8*)(Hj + 32);
            half8 Al0 = *(const half8*)(Lj);
            half8 Al1 = *(const half8*)(Lj + 32);
            f32x4 acc = {0.f, 0.f, 0.f, 0.f};
            acc = __builtin_amdgcn_mfma_f32_16x16x32_f16(Ah0, Bh0, acc, 0, 0, 0);
            acc = __builtin_amdgcn_mfma_f32_16x16x32_f16(Ah1, Bh1, acc, 0, 0, 0);
            acc = __builtin_amdgcn_mfma_f32_16x16x32_f16(Al0, Bh0, acc, 0, 0, 0);
            acc = __builtin_amdgcn_mfma_f32_16x16x32_f16(Al1, Bh1, acc, 0, 0, 0);
            acc = __builtin_amdgcn_mfma_f32_16x16x32_f16(Ah0, Bl0, acc, 0, 0, 0);
            acc = __builtin_amdgcn_mfma_f32_16x16x32_f16(Ah1, Bl1, acc, 0, 0, 0);
            // (L*L term dropped: ~3e-7, below fp32 accumulation noise)
            int jb = jt * 64 + g * 16 + quad * 4;   // lane holds j = jb..jb+3, col = irow
            float4 xn4 = *(const float4*)&xnb[jb];
            d[g * 4 + 0] = 2.f * acc[0] - xn4.x; jd[g * 4 + 0] = jb + 0;
            d[g * 4 + 1] = 2.f * acc[1] - xn4.y; jd[g * 4 + 1] = jb + 1;
            d[g * 4 + 2] = 2.f * acc[2] - xn4.z; jd[g * 4 + 2] = jb + 2;
            d[g * 4 + 3] = 2.f * acc[3] - xn4.w; jd[g * 4 + 3] = jb + 3;
        }
        // bitonic sort-16 ascending (static network after unroll)
        #pragma unroll
        for (int k = 2; k <= 16; k <<= 1) {
            #pragma unroll
            for (int jj = k >> 1; jj > 0; jj >>= 1) {
                #pragma unroll
                for (int i = 0; i < 16; ++i) {
                    int lo = i ^ jj;
                    if (lo > i) {
                        if ((i & k) == 0) cas_asc(d[i], jd[i], d[lo], jd[lo]);
                        else              cas_asc(d[lo], jd[lo], d[i], jd[i]);
                    }
                }
            }
        }
        // exact top-16 of (kv ∪ d): max-trick (result bitonic), then clean
        #pragma unroll
        for (int i = 0; i < 16; ++i) {
            bool take = kv[i] >= d[15 - i];
            kv[i] = take ? kv[i] : d[15 - i];
            kj[i] = take ? kj[i] : jd[15 - i];
        }
        #pragma unroll
        for (int jj = 8; jj > 0; jj >>= 1) {
            #pragma unroll
            for (int i = 0; i < 16; ++i) {
                int lo = i ^ jj;
                if (lo > i) cas_asc(kv[i], kj[i], kv[lo], kj[lo]);
            }
        }
    }
    // dump sorted-16 per quad, merge 4 lists per row (value desc, tie: smaller j)
    #pragma unroll
    for (int q = 0; q < 16; ++q) {
        ldsMV[w][(lane16 * 4 + quad) * 16 + q] = kv[q];
        ldsMJ[w][(lane16 * 4 + quad) * 16 + q] = kj[q];
    }
    __syncthreads();
    if (quad == 0) {
        const float* MV = &ldsMV[w][lane16 * 64];
        const int*   MJ = &ldsMJ[w][lane16 * 64];
        int p0 = 15, p1 = 15, p2 = 15, p3 = 15;
        int* op = idx_out + ((size_t)bq * 512 + irow) * 16;
        for (int t = 0; t < K; ++t) {
            float bv = -3.4e38f; int bj = 0x7fffffff; int bc = -1;
            { float v = MV[p0]; int j = MJ[p0];
              if (v > bv || (v == bv && j < bj)) { bv = v; bj = j; bc = 0; } }
            { float v = MV[16 + p1]; int j = MJ[16 + p1];
              if (v > bv || (v == bv && j < bj)) { bv = v; bj = j; bc = 1; } }
            { float v = MV[32 + p2]; int j = MJ[32 + p2];
              if (v > bv || (v == bv && j < bj)) { bv = v; bj = j; bc = 2; } }
            { float v = MV[48 + p3]; int j = MJ[48 + p3];
              if (v > bv || (v == bv && j < bj)) { bv = v; bj = j; bc = 3; } }
            if (bc == 0) --p0; else if (bc == 1) --p1; else if (bc == 2) --p2; else --p3;
            op[t] = bj;
        }
    }
}

// ---------------- AB[bq] = [W1; W2-W1] (128x64) @ (X[bq] + vec) (64x512) ----------------
__global__ __launch_bounds__(256) void gemm_kernel(
    const float* __restrict__ X, const float* __restrict__ W,
    const float* __restrict__ vec, float* __restrict__ AB)
{
    __shared__ float ldsW[64 * 128];   // [c][o]
    __shared__ float ldsX[64 * 64];    // [c][i]
    int bq = blockIdx.x >> 3, itile = blockIdx.x & 7;
    int tid = threadIdx.x;
    const float* Xb = X + (size_t)bq * 32768;
    for (int p = 0; p < 32; ++p) {
        int t = p * 256 + tid;         // t = c*128 + o
        int c = t >> 7, o = t & 127;
        float val;
        if (o < 64) val = W[o * 128 + c];                                  // W1
        else        val = W[(o - 64) * 128 + 64 + c] - W[(o - 64) * 128 + c]; // W2-W1
        ldsW[t] = val;
    }
    int ibase = itile * 64;
    for (int p = 0; p < 16; ++p) {
        int t = p * 256 + tid;
        int c = t >> 6, il = t & 63;
        float v = Xb[c * 512 + ibase + il];
        if (vec) v += vec[bq * 64 + c];
        ldsX[t] = v;
    }
    __syncthreads();
    int tj = tid & 15, to = tid >> 4;
    int i0 = 4 * tj, o0 = 8 * to;
    float acc[8][4];
    #pragma unroll
    for (int a = 0; a < 8; ++a)
        #pragma unroll
        for (int b2 = 0; b2 < 4; ++b2) acc[a][b2] = 0.f;
    for (int c = 0; c < 64; ++c) {
        float4 xv  = *(float4*)&ldsX[c * 64 + i0];
        float4 w0v = *(float4*)&ldsW[c * 128 + o0];
        float4 w1v = *(float4*)&ldsW[c * 128 + o0 + 4];
        acc[0][0] += w0v.x * xv.x; acc[0][1] += w0v.x * xv.y; acc[0][2] += w0v.x * xv.z; acc[0][3] += w0v.x * xv.w;
        acc[1][0] += w0v.y * xv.x; acc[1][1] += w0v.y * xv.y; acc[1][2] += w0v.y * xv.z; acc[1][3] += w0v.y * xv.w;
        acc[2][0] += w0v.z * xv.x; acc[2][1] += w0v.z * xv.y; acc[2][2] += w0v.z * xv.z; acc[2][3] += w0v.z * xv.w;
        acc[3][0] += w0v.w * xv.x; acc[3][1] += w0v.w * xv.y; acc[3][2] += w0v.w * xv.z; acc[3][3] += w0v.w * xv.w;
        acc[4][0] += w1v.x * xv.x; acc[4][1] += w1v.x * xv.y; acc[4][2] += w1v.x * xv.z; acc[4][3] += w1v.x * xv.w;
        acc[5][0] += w1v.y * xv.x; acc[5][1] += w1v.y * xv.y; acc[5][2] += w1v.y * xv.z; acc[5][3] += w1v.y * xv.w;
        acc[6][0] += w1v.z * xv.x; acc[6][1] += w1v.z * xv.y; acc[6][2] += w1v.z * xv.z; acc[6][3] += w1v.z * xv.w;
        acc[7][0] += w1v.w * xv.x; acc[7][1] += w1v.w * xv.y; acc[7][2] += w1v.w * xv.z; acc[7][3] += w1v.w * xv.w;
    }
    float* out = AB + (size_t)bq * 65536 + ibase + i0;
    #pragma unroll
    for (int a = 0; a < 8; ++a) {
        float4 sv; sv.x = acc[a][0]; sv.y = acc[a][1]; sv.z = acc[a][2]; sv.w = acc[a][3];
        *(float4*)(out + (size_t)(o0 + a) * 512) = sv;
    }
}

// ---------------- branch epilogue v3: grid (96,4), 16 o's per block ----------------
template<int ACC>
__global__ __launch_bounds__(256) void branch_reduce_kernel(
    const float* __restrict__ AB, const int* __restrict__ idx,
    const float* __restrict__ g, const float* __restrict__ bb,
    const float* __restrict__ mm, const float* __restrict__ vv,
    float* __restrict__ out_p, float* __restrict__ vec_out)
{
    __shared__ float ldsA[16 * 512];       // 32 KB: A-chunk [o][i]
    __shared__ int   ldsIdx[512 * 10];     // 20 KB
    int bq = blockIdx.x, ob = blockIdx.y * 16;
    int tid = threadIdx.x;
    int w = tid >> 6, ln = tid & 63;
    for (int p = 0; p < 20; ++p) {
        int t = p * 256 + tid;
        int i = t / 10, q = t - i * 10;
        ldsIdx[t] = idx[((size_t)bq * 512 + i) * 16 + q];
    }
    const float* ABb = AB + (size_t)bq * 65536;
    for (int p = 0; p < 8; ++p) {
        int t = p * 256 + tid;             // float4 index into 16*512
        int o = t >> 7, i4 = t & 127;
        *(float4*)&ldsA[o * 512 + i4 * 4] = *(const float4*)&ABb[(size_t)(ob + o) * 512 + i4 * 4];
    }
    float ssr[4], str[4];
    #pragma unroll
    for (int oo = 0; oo < 4; ++oo) {
        int o = ob + w * 4 + oo;
        float sc = g[o] / sqrtf(vv[o] + EPS);
        ssr[oo] = sc;
        str[oo] = bb[o] - mm[o] * sc;
    }
    __syncthreads();
    float omax[4], osum[4];
    #pragma unroll
    for (int oo = 0; oo < 4; ++oo) { omax[oo] = -3.4e38f; osum[oo] = 0.f; }
    const float* Aw = ldsA + (w * 4) * 512;
    for (int s = 0; s < 8; ++s) {
        int i = ln + 64 * s;
        int idr[10];
        const int* ip = &ldsIdx[i * 10];
        #pragma unroll
        for (int q = 0; q < 10; ++q) idr[q] = ip[q];
        #pragma unroll
        for (int oo = 0; oo < 4; ++oo) {
            const float* Ao = Aw + oo * 512;
            float mx = Ao[idr[0]];
            #pragma unroll
            for (int q = 1; q < 10; ++q) mx = fmaxf(mx, Ao[idr[q]]);
            float Bv = ABb[(size_t)(64 + ob + w * 4 + oo) * 512 + i];
            float val = (mx + Bv) * ssr[oo] + str[oo];
            float y = val > 0.f ? val : 0.2f * val;
            omax[oo] = fmaxf(omax[oo], y);
            osum[oo] += y;
        }
    }
    #pragma unroll
    for (int oo = 0; oo < 4; ++oo) {
        float M = omax[oo], S = osum[oo];
        #pragma unroll
        for (int off = 32; off >= 1; off >>= 1) {
            M = fmaxf(M, __shfl_down(M, off));
            S += __shfl_down(S, off);
        }
        if (ln == 0) {
            int o = ob + w * 4 + oo;
            float* po = out_p + bq * 128;
            if (ACC) {
                po[o] += M;
                po[64 + o] += S * (1.f / 512.f);
            } else {
                po[o] = M;
                po[64 + o] = S * (1.f / 512.f);
                vec_out[bq * 64 + o] = M;
            }
        }
    }
}

// ---------------- corre_binar: f, masks ----------------
__global__ __launch_bounds__(256) void corre_kernel(
    const float* __restrict__ x, const float* __restrict__ x0vec,
    const float* __restrict__ w_reduce, const int* __restrict__ idx8,
    float* __restrict__ fbuf, float* __restrict__ masks)
{
    __shared__ float sxv[64], sq[64], ss[512], sfk[512];
    int bq = blockIdx.x, tid = threadIdx.x;
    int row = src_row(bq);
    const float* Xb = x + (size_t)row * 32768;
    if (tid < 64) sxv[tid] = x0vec[bq * 64 + tid];
    __syncthreads();
    if (tid < 64) {
        float a = 0.f;
        for (int c = 0; c < 64; ++c) a += w_reduce[tid * 64 + c] * sxv[c];
        sq[tid] = a;
    }
    __syncthreads();
    for (int i = tid; i < 512; i += 256) {
        float a = 0.f;
        for (int c = 0; c < 64; ++c) a += sq[c] * Xb[c * 512 + i];
        a *= 0.125f;                    // 1/sqrt(64)
        ss[i] = a;
        fbuf[bq * 512 + i] = a;
    }
    __syncthreads();
    for (int i = tid; i < 512; i += 256) {
        float a = ss[i];
        const int* ip = idx8 + ((size_t)bq * 512 + i) * 16;
        for (int q = 0; q < 8; ++q) a += ss[ip[q]];
        sfk[i] = a;
    }
    masks[bq * 512 + tid] = 1.0f;
    masks[bq * 512 + tid + 256] = 1.0f;
    __syncthreads();
    if (tid == 0) {
        float best = sfk[0]; int bi = 0;
        for (int i = 1; i < 512; ++i) if (sfk[i] > best) { best = sfk[i]; bi = i; }
        masks[bq * 512 + bi] = 0.f;
        const int* ip = idx8 + ((size_t)bq * 512 + bi) * 16;
        for (int q = 0; q < 8; ++q) masks[bq * 512 + ip[q]] = 0.f;
    }
}

// ---------------- erase1 ----------------
__global__ __launch_bounds__(256) void erase1_kernel(
    const float* __restrict__ x, const float* __restrict__ masks,
    const float* __restrict__ fbuf,
    const float* __restrict__ w_e, const float* __restrict__ b_e,
    const float* __restrict__ g_e, const float* __restrict__ be_e,
    const float* __restrict__ m_e, const float* __restrict__ v_e,
    float* __restrict__ x1e)
{
    __shared__ float sw[512];
    __shared__ float smk[512];
    __shared__ float red[256];
    __shared__ float sres[64];
    __shared__ float sy[64];
    int bq = blockIdx.x, tid = threadIdx.x;
    int row = src_row(bq);
    const float* Xb = x + (size_t)row * 32768;
    float f0 = fbuf[bq * 512 + tid], f1 = fbuf[bq * 512 + tid + 256];
    float mk0 = masks[bq * 512 + tid], mk1 = masks[bq * 512 + tid + 256];
    smk[tid] = mk0; smk[tid + 256] = mk1;
    float s0 = f0 - (1.f - mk0) * 1e8f, s1 = f1 - (1.f - mk1) * 1e8f;
    red[tid] = fmaxf(s0, s1);
    __syncthreads();
    for (int off = 128; off >= 1; off >>= 1) {
        if (tid < off) red[tid] = fmaxf(red[tid], red[tid + off]);
        __syncthreads();
    }
    float mx = red[0];
    __syncthreads();
    float e0 = expf(s0 - mx), e1 = expf(s1 - mx);
    red[tid] = e0 + e1;
    __syncthreads();
    for (int off = 128; off >= 1; off >>= 1) {
        if (tid < off) red[tid] = red[tid] + red[tid + off];
        __syncthreads();
    }
    float inv = 1.f / red[0];
    __syncthreads();
    sw[tid] = e0 * inv; sw[tid + 256] = e1 * inv;
    __syncthreads();
    int c = tid >> 2, p = tid & 3;
    {
        float a = 0.f;
        const float* xr = Xb + c * 512 + p * 128;
        const float* wr = &sw[p * 128];
        for (int ii = 0; ii < 128; ++ii) a += xr[ii] * wr[ii];
        red[tid] = a;
    }
    __syncthreads();
    if (p == 0) sres[c] = red[tid] + red[tid + 1] + red[tid + 2] + red[tid + 3];
    __syncthreads();
    if (tid < 64) {
        float a = b_e[tid];
        for (int cc = 0; cc < 64; ++cc) a += w_e[tid * 64 + cc] * sres[cc];
        float sc = g_e[tid] / sqrtf(v_e[tid] + EPS);
        sy[tid] = (a - m_e[tid]) * sc + be_e[tid];
    }
    __syncthreads();
    float* ob = x1e + (size_t)bq * 32768;
    for (int p2 = 0; p2 < 128; ++p2) {
        int e = p2 * 256 + tid;
        int cc = e >> 9, i = e & 511;
        ob[e] = Xb[e] * smk[i] + sy[cc];
    }
}

extern "C" void kernel_launch(void* const* d_in, const int* in_sizes, int n_in,
                              void* d_out, int out_size, void* d_ws, size_t ws_size,
                              hipStream_t stream)
{
    const float* x        = (const float*)d_in[0];
    const float* w_reduce = (const float*)d_in[1];
    const float* w_erase  = (const float*)d_in[2];
    const float* b_erase  = (const float*)d_in[3];
    const float* g_erase  = (const float*)d_in[4];
    const float* be_erase = (const float*)d_in[5];
    const float* m_erase  = (const float*)d_in[6];
    const float* v_erase  = (const float*)d_in[7];
    const float* w0 = (const float*)d_in[8];
    const float* g0 = (const float*)d_in[9];
    const float* b0 = (const float*)d_in[10];
    const float* m0 = (const float*)d_in[11];
    const float* v0 = (const float*)d_in[12];
    const float* w1 = (const float*)d_in[13];
    const float* g1 = (const float*)d_in[14];
    const float* b1 = (const float*)d_in[15];
    const float* m1 = (const float*)d_in[16];
    const float* v1 = (const float*)d_in[17];
    float* out = (float*)d_out;
    char* ws = (char*)d_ws;

    float* xbuf  = (float*)(ws);                 // 12.58 MB: x1e fp32 [c][n]
    float* AB    = (float*)(ws + 12582912);      // 25.17 MB: AB, overlaid with h/l
    _Float16* h  = (_Float16*)(ws + 12582912);   //   h: 6.29 MB (alive only when AB dead)
    _Float16* lo = (_Float16*)(ws + 18874368);   //   l: 6.29 MB
    int*   idxA  = (int*)(ws + 37748736);        // 3.15 MB: k=10 idx (stride 16)
    int*   idx8  = (int*)(ws + 40894464);        // 3.15 MB: k=8 idx
    float* xn    = (float*)(ws + 44040192);      // 192 KB: col norms
    float* y0vec = (float*)(ws + 44236800);      // 24 KB
    float* x0vec = (float*)(ws + 44261376);      // 24 KB
    float* fbuf  = (float*)(ws + 44285952);      // 192 KB
    float* masks = (float*)(ws + 44482560);      // 192 KB

    (void)in_sizes; (void)n_in; (void)out_size; (void)ws_size;

    // x0 = erase(x, ones, ones) = x + y0vec
    erase0_kernel<<<96, 256, 0, stream>>>(x, w_erase, b_erase, g_erase, be_erase, m_erase, v_erase, y0vec);
    // branch 0
    prep_kernel<<<768, 256, 0, stream>>>(x, y0vec, 0, h, lo, xn);
    knn_mfma_kernel<10><<<768, 256, 0, stream>>>(h, lo, xn, idxA);
    gemm_kernel<<<768, 256, 0, stream>>>(x, w0, y0vec, AB);
    branch_reduce_kernel<0><<<dim3(96, 4), 256, 0, stream>>>(AB, idxA, g0, b0, m0, v0, out, x0vec);
    // corre_binar on x1seq (x with t-shift remap)
    prep_kernel<<<768, 256, 0, stream>>>(x, nullptr, 1, h, lo, xn);
    knn_mfma_kernel<8><<<768, 256, 0, stream>>>(h, lo, xn, idx8);
    corre_kernel<<<96, 256, 0, stream>>>(x, x0vec, w_reduce, idx8, fbuf, masks);
    // x1e = erase(x1seq, masks, f)
    erase1_kernel<<<96, 256, 0, stream>>>(x, masks, fbuf, w_erase, b_erase, g_erase, be_erase, m_erase, v_erase, xbuf);
    // branch 1
    prep_kernel<<<768, 256, 0, stream>>>(xbuf, nullptr, 0, h, lo, xn);
    knn_mfma_kernel<10><<<768, 256, 0, stream>>>(h, lo, xn, idxA);
    gemm_kernel<<<768, 256, 0, stream>>>(xbuf, w1, nullptr, AB);
    branch_reduce_kernel<1><<<dim3(96, 4), 256, 0, stream>>>(AB, idxA, g1, b1, m1, v1, out, nullptr);
}

// Round 5
// 465.684 us; speedup vs baseline: 2.0018x; 1.0687x over previous
//
#include <hip/hip_runtime.h>
#include <math.h>

#define EPS 1e-5f

typedef _Float16 half8 __attribute__((ext_vector_type(8)));
typedef float f32x4 __attribute__((ext_vector_type(4)));

// bq in [0,96): b = bq/12, t = bq%12; x1seq row = b*12 + min(t+1, 11)
__device__ __forceinline__ int src_row(int bq) {
    int b = bq / 12, t = bq - b * 12;
    int t2 = (t + 1 < 12) ? (t + 1) : 11;
    return b * 12 + t2;
}

// ---------------- erase0: y0vec[bq][o] = BN(W_e @ mean_n(x) + b_e) ----------------
__global__ __launch_bounds__(256) void erase0_kernel(
    const float* __restrict__ x, const float* __restrict__ w_e,
    const float* __restrict__ b_e, const float* __restrict__ g_e,
    const float* __restrict__ be_e, const float* __restrict__ m_e,
    const float* __restrict__ v_e, float* __restrict__ y0vec)
{
    __shared__ float part[256];
    __shared__ float res[64];
    int bq = blockIdx.x, tid = threadIdx.x;
    int c = tid >> 2, p = tid & 3;
    const float* xb = x + (size_t)bq * 32768 + c * 512 + p * 128;
    float acc = 0.f;
    for (int ii = 0; ii < 128; ii += 4) {
        float4 v = *(const float4*)(xb + ii);
        acc += v.x + v.y + v.z + v.w;
    }
    part[tid] = acc;
    __syncthreads();
    if (p == 0) res[c] = (part[tid] + part[tid+1] + part[tid+2] + part[tid+3]) * (1.f/512.f);
    __syncthreads();
    if (tid < 64) {
        float a = b_e[tid];
        for (int cc = 0; cc < 64; ++cc) a += w_e[tid*64+cc] * res[cc];
        float s = g_e[tid] / sqrtf(v_e[tid] + EPS);
        y0vec[bq*64 + tid] = (a - m_e[tid]) * s + be_e[tid];
    }
}

// ---------------- prep dual: fp16 split (h,l) [n][c] + fp32 colnorms, both inputs ----------------
// grid = 1536. blockIdx = q*96 + bq, q=0..15: itile=q&7, half=q>>3.
// half 0: row=bq, +vec (x0);  half 1: row=src_row(bq) (x1seq).
// XCD swizzle: same-bq blocks are 96 apart -> same blockIdx%8 -> same XCD L2.
__global__ __launch_bounds__(256) void prep_kernel(
    const float* __restrict__ X, const float* __restrict__ vec,
    _Float16* __restrict__ H0, _Float16* __restrict__ L0, float* __restrict__ xn0,
    _Float16* __restrict__ H1, _Float16* __restrict__ L1, float* __restrict__ xn1)
{
    __shared__ float lds[64 * 65];     // [c][col] pad
    __shared__ float xnp[4 * 64];
    int raw = blockIdx.x;
    int bq = raw % 96;
    int q = raw / 96;
    int ct = q & 7, half = q >> 3;
    int row = half ? src_row(bq) : bq;
    _Float16* H = half ? H1 : H0;
    _Float16* L = half ? L1 : L0;
    float* xn = half ? xn1 : xn0;
    const float* vp = half ? nullptr : vec;
    const float* Xb = X + (size_t)row * 32768 + ct * 64;
    int tid = threadIdx.x;
    for (int p = 0; p < 16; ++p) {
        int t = p * 256 + tid;
        int c = t >> 6, col = t & 63;
        float v = Xb[c * 512 + col];
        if (vp) v += vp[bq * 64 + c];
        lds[c * 65 + col] = v;
    }
    __syncthreads();
    int col = tid & 63, g = tid >> 6;       // g: group of 16 channels
    half8 hv[2], lv[2];
    float s = 0.f;
    #pragma unroll
    for (int k = 0; k < 16; ++k) {
        int c = g * 16 + k;
        float v = lds[c * 65 + col];
        _Float16 h = (_Float16)v;
        _Float16 lo = (_Float16)(v - (float)h);
        hv[k >> 3][k & 7] = h;
        lv[k >> 3][k & 7] = lo;
        s += v * v;
    }
    size_t obase = ((size_t)bq * 512 + ct * 64 + col) * 64 + g * 16;
    *(half8*)(H + obase) = hv[0];
    *(half8*)(H + obase + 8) = hv[1];
    *(half8*)(L + obase) = lv[0];
    *(half8*)(L + obase + 8) = lv[1];
    xnp[g * 64 + col] = s;
    __syncthreads();
    if (tid < 64)
        xn[bq * 512 + ct * 64 + tid] =
            xnp[tid] + xnp[64 + tid] + xnp[128 + tid] + xnp[192 + tid];
}

// ---------------- kNN: transposed MFMA + bitonic sort-16 selection (dual-capable) ----------------
// grid = 1536 (dual) or 768 (single). blockIdx = q*96+bq, itile=q&7, half=q>>3.
// Wave w owns i-rows itile*64+w*16+lane16; selection keeps top-16 always; k at merge.
__global__ __launch_bounds__(256) void knn_kernel(
    const _Float16* __restrict__ H0, const _Float16* __restrict__ L0,
    const float* __restrict__ xn0, int* __restrict__ idx0, int k0,
    const _Float16* __restrict__ H1, const _Float16* __restrict__ L1,
    const float* __restrict__ xn1, int* __restrict__ idx1, int k1)
{
    __shared__ float ldsMV[4][64 * 17];   // per wave: 64 lists x 16 vals, pad 17
    __shared__ int   ldsMJ[4][64 * 17];
    int raw = blockIdx.x;
    int bq = raw % 96;
    int q = raw / 96;
    int itile = q & 7, half = q >> 3;
    const _Float16* H = half ? H1 : H0;
    const _Float16* L = half ? L1 : L0;
    const float* xn = half ? xn1 : xn0;
    int* idx_out = half ? idx1 : idx0;
    int K = half ? k1 : k0;
    int tid = threadIdx.x, w = tid >> 6, l = tid & 63;
    int lane16 = l & 15, quad = l >> 4;
    const size_t base = (size_t)bq * 512 * 64;
    int irow = itile * 64 + w * 16 + lane16;
    // B operand = this wave's i-rows (fixed in registers)
    const _Float16* Hi = H + base + (size_t)irow * 64 + quad * 8;
    const _Float16* Li = L + base + (size_t)irow * 64 + quad * 8;
    half8 Bh0 = *(const half8*)(Hi);
    half8 Bh1 = *(const half8*)(Hi + 32);
    half8 Bl0 = *(const half8*)(Li);
    half8 Bl1 = *(const half8*)(Li + 32);

    float kv[16]; int kj[16];              // running top-16, ascending (kv[15]=best)
    #pragma unroll
    for (int qq = 0; qq < 16; ++qq) { kv[qq] = -3.4e38f; kj[qq] = 0; }

    auto cas_asc = [](float& va, int& ja, float& vb, int& jb2) {
        bool sw = va > vb;
        float tv = va; int tj = ja;
        va = sw ? vb : va; ja = sw ? jb2 : ja;
        vb = sw ? tv : vb; jb2 = sw ? tj : jb2;
    };

    const float* xnb = xn + bq * 512;
    for (int jt = 0; jt < 8; ++jt) {
        float d[16]; int jd[16];
        #pragma unroll
        for (int g = 0; g < 4; ++g) {
            int jrow = jt * 64 + g * 16 + lane16;
            const _Float16* Hj = H + base + (size_t)jrow * 64 + quad * 8;
            const _Float16* Lj = L + base + (size_t)jrow * 64 + quad * 8;
            half8 Ah0 = *(const half8*)(Hj);
            half8 Ah1 = *(const half8*)(Hj + 32);
            half8 Al0 = *(const half8*)(Lj);
            half8 Al1 = *(const half8*)(Lj + 32);
            f32x4 acc = {0.f, 0.f, 0.f, 0.f};
            acc = __builtin_amdgcn_mfma_f32_16x16x32_f16(Ah0, Bh0, acc, 0, 0, 0);
            acc = __builtin_amdgcn_mfma_f32_16x16x32_f16(Ah1, Bh1, acc, 0, 0, 0);
            acc = __builtin_amdgcn_mfma_f32_16x16x32_f16(Al0, Bh0, acc, 0, 0, 0);
            acc = __builtin_amdgcn_mfma_f32_16x16x32_f16(Al1, Bh1, acc, 0, 0, 0);
            acc = __builtin_amdgcn_mfma_f32_16x16x32_f16(Ah0, Bl0, acc, 0, 0, 0);
            acc = __builtin_amdgcn_mfma_f32_16x16x32_f16(Ah1, Bl1, acc, 0, 0, 0);
            // (L*L term dropped: ~3e-7, below fp32 accumulation noise)
            int jb = jt * 64 + g * 16 + quad * 4;   // lane holds j = jb..jb+3, col = irow
            float4 xn4 = *(const float4*)&xnb[jb];
            d[g * 4 + 0] = 2.f * acc[0] - xn4.x; jd[g * 4 + 0] = jb + 0;
            d[g * 4 + 1] = 2.f * acc[1] - xn4.y; jd[g * 4 + 1] = jb + 1;
            d[g * 4 + 2] = 2.f * acc[2] - xn4.z; jd[g * 4 + 2] = jb + 2;
            d[g * 4 + 3] = 2.f * acc[3] - xn4.w; jd[g * 4 + 3] = jb + 3;
        }
        // bitonic sort-16 ascending (static network after unroll)
        #pragma unroll
        for (int k = 2; k <= 16; k <<= 1) {
            #pragma unroll
            for (int jj = k >> 1; jj > 0; jj >>= 1) {
                #pragma unroll
                for (int i = 0; i < 16; ++i) {
                    int lo = i ^ jj;
                    if (lo > i) {
                        if ((i & k) == 0) cas_asc(d[i], jd[i], d[lo], jd[lo]);
                        else              cas_asc(d[lo], jd[lo], d[i], jd[i]);
                    }
                }
            }
        }
        // exact top-16 of (kv ∪ d): max-trick (result bitonic), then clean
        #pragma unroll
        for (int i = 0; i < 16; ++i) {
            bool take = kv[i] >= d[15 - i];
            kv[i] = take ? kv[i] : d[15 - i];
            kj[i] = take ? kj[i] : jd[15 - i];
        }
        #pragma unroll
        for (int jj = 8; jj > 0; jj >>= 1) {
            #pragma unroll
            for (int i = 0; i < 16; ++i) {
                int lo = i ^ jj;
                if (lo > i) cas_asc(kv[i], kj[i], kv[lo], kj[lo]);
            }
        }
    }
    // dump sorted-16 per quad (pad-17 stride: conflict-free), merge 4 lists per row
    #pragma unroll
    for (int qq = 0; qq < 16; ++qq) {
        ldsMV[w][(lane16 * 4 + quad) * 17 + qq] = kv[qq];
        ldsMJ[w][(lane16 * 4 + quad) * 17 + qq] = kj[qq];
    }
    __syncthreads();
    if (quad == 0) {
        const float* MV = &ldsMV[w][lane16 * 68];
        const int*   MJ = &ldsMJ[w][lane16 * 68];
        int p0 = 15, p1 = 15, p2 = 15, p3 = 15;
        int* op = idx_out + ((size_t)bq * 512 + irow) * 16;
        for (int t = 0; t < K; ++t) {
            float bv = -3.4e38f; int bj = 0x7fffffff; int bc = -1;
            { float v = MV[p0]; int j = MJ[p0];
              if (v > bv || (v == bv && j < bj)) { bv = v; bj = j; bc = 0; } }
            { float v = MV[17 + p1]; int j = MJ[17 + p1];
              if (v > bv || (v == bv && j < bj)) { bv = v; bj = j; bc = 1; } }
            { float v = MV[34 + p2]; int j = MJ[34 + p2];
              if (v > bv || (v == bv && j < bj)) { bv = v; bj = j; bc = 2; } }
            { float v = MV[51 + p3]; int j = MJ[51 + p3];
              if (v > bv || (v == bv && j < bj)) { bv = v; bj = j; bc = 3; } }
            if (bc == 0) --p0; else if (bc == 1) --p1; else if (bc == 2) --p2; else --p3;
            op[t] = bj;
        }
    }
}

// ---------------- AB[bq] = [W1; W2-W1] (128x64) @ (X[bq] + vec) (64x512) ----------------
// blockIdx = itile*96 + bq (XCD swizzle).
__global__ __launch_bounds__(256) void gemm_kernel(
    const float* __restrict__ X, const float* __restrict__ W,
    const float* __restrict__ vec, float* __restrict__ AB)
{
    __shared__ float ldsW[64 * 128];   // [c][o]
    __shared__ float ldsX[64 * 64];    // [c][i]
    int raw = blockIdx.x;
    int bq = raw % 96;
    int itile = raw / 96;
    int tid = threadIdx.x;
    const float* Xb = X + (size_t)bq * 32768;
    for (int p = 0; p < 32; ++p) {
        int t = p * 256 + tid;         // t = c*128 + o
        int c = t >> 7, o = t & 127;
        float val;
        if (o < 64) val = W[o * 128 + c];                                  // W1
        else        val = W[(o - 64) * 128 + 64 + c] - W[(o - 64) * 128 + c]; // W2-W1
        ldsW[t] = val;
    }
    int ibase = itile * 64;
    for (int p = 0; p < 16; ++p) {
        int t = p * 256 + tid;
        int c = t >> 6, il = t & 63;
        float v = Xb[c * 512 + ibase + il];
        if (vec) v += vec[bq * 64 + c];
        ldsX[t] = v;
    }
    __syncthreads();
    int tj = tid & 15, to = tid >> 4;
    int i0 = 4 * tj, o0 = 8 * to;
    float acc[8][4];
    #pragma unroll
    for (int a = 0; a < 8; ++a)
        #pragma unroll
        for (int b2 = 0; b2 < 4; ++b2) acc[a][b2] = 0.f;
    for (int c = 0; c < 64; ++c) {
        float4 xv  = *(float4*)&ldsX[c * 64 + i0];
        float4 w0v = *(float4*)&ldsW[c * 128 + o0];
        float4 w1v = *(float4*)&ldsW[c * 128 + o0 + 4];
        acc[0][0] += w0v.x * xv.x; acc[0][1] += w0v.x * xv.y; acc[0][2] += w0v.x * xv.z; acc[0][3] += w0v.x * xv.w;
        acc[1][0] += w0v.y * xv.x; acc[1][1] += w0v.y * xv.y; acc[1][2] += w0v.y * xv.z; acc[1][3] += w0v.y * xv.w;
        acc[2][0] += w0v.z * xv.x; acc[2][1] += w0v.z * xv.y; acc[2][2] += w0v.z * xv.z; acc[2][3] += w0v.z * xv.w;
        acc[3][0] += w0v.w * xv.x; acc[3][1] += w0v.w * xv.y; acc[3][2] += w0v.w * xv.z; acc[3][3] += w0v.w * xv.w;
        acc[4][0] += w1v.x * xv.x; acc[4][1] += w1v.x * xv.y; acc[4][2] += w1v.x * xv.z; acc[4][3] += w1v.x * xv.w;
        acc[5][0] += w1v.y * xv.x; acc[5][1] += w1v.y * xv.y; acc[5][2] += w1v.y * xv.z; acc[5][3] += w1v.y * xv.w;
        acc[6][0] += w1v.z * xv.x; acc[6][1] += w1v.z * xv.y; acc[6][2] += w1v.z * xv.z; acc[6][3] += w1v.z * xv.w;
        acc[7][0] += w1v.w * xv.x; acc[7][1] += w1v.w * xv.y; acc[7][2] += w1v.w * xv.z; acc[7][3] += w1v.w * xv.w;
    }
    float* out = AB + (size_t)bq * 65536 + ibase + i0;
    #pragma unroll
    for (int a = 0; a < 8; ++a) {
        float4 sv; sv.x = acc[a][0]; sv.y = acc[a][1]; sv.z = acc[a][2]; sv.w = acc[a][3];
        *(float4*)(out + (size_t)(o0 + a) * 512) = sv;
    }
}

// ---------------- branch epilogue: grid (96,4), 16 o's per block ----------------
template<int ACC>
__global__ __launch_bounds__(256) void branch_reduce_kernel(
    const float* __restrict__ AB, const int* __restrict__ idx,
    const float* __restrict__ g, const float* __restrict__ bb,
    const float* __restrict__ mm, const float* __restrict__ vv,
    float* __restrict__ out_p, float* __restrict__ vec_out)
{
    __shared__ float ldsA[16 * 512];       // 32 KB: A-chunk [o][i]
    __shared__ int   ldsIdx[512 * 10];     // 20 KB
    int bq = blockIdx.x, ob = blockIdx.y * 16;
    int tid = threadIdx.x;
    int w = tid >> 6, ln = tid & 63;
    for (int p = 0; p < 20; ++p) {
        int t = p * 256 + tid;
        int i = t / 10, q = t - i * 10;
        ldsIdx[t] = idx[((size_t)bq * 512 + i) * 16 + q];
    }
    const float* ABb = AB + (size_t)bq * 65536;
    for (int p = 0; p < 8; ++p) {
        int t = p * 256 + tid;             // float4 index into 16*512
        int o = t >> 7, i4 = t & 127;
        *(float4*)&ldsA[o * 512 + i4 * 4] = *(const float4*)&ABb[(size_t)(ob + o) * 512 + i4 * 4];
    }
    float ssr[4], str[4];
    #pragma unroll
    for (int oo = 0; oo < 4; ++oo) {
        int o = ob + w * 4 + oo;
        float sc = g[o] / sqrtf(vv[o] + EPS);
        ssr[oo] = sc;
        str[oo] = bb[o] - mm[o] * sc;
    }
    __syncthreads();
    float omax[4], osum[4];
    #pragma unroll
    for (int oo = 0; oo < 4; ++oo) { omax[oo] = -3.4e38f; osum[oo] = 0.f; }
    const float* Aw = ldsA + (w * 4) * 512;
    for (int s = 0; s < 8; ++s) {
        int i = ln + 64 * s;
        int idr[10];
        const int* ip = &ldsIdx[i * 10];
        #pragma unroll
        for (int q = 0; q < 10; ++q) idr[q] = ip[q];
        #pragma unroll
        for (int oo = 0; oo < 4; ++oo) {
            const float* Ao = Aw + oo * 512;
            float mx = Ao[idr[0]];
            #pragma unroll
            for (int q = 1; q < 10; ++q) mx = fmaxf(mx, Ao[idr[q]]);
            float Bv = ABb[(size_t)(64 + ob + w * 4 + oo) * 512 + i];
            float val = (mx + Bv) * ssr[oo] + str[oo];
            float y = val > 0.f ? val : 0.2f * val;
            omax[oo] = fmaxf(omax[oo], y);
            osum[oo] += y;
        }
    }
    #pragma unroll
    for (int oo = 0; oo < 4; ++oo) {
        float M = omax[oo], S = osum[oo];
        #pragma unroll
        for (int off = 32; off >= 1; off >>= 1) {
            M = fmaxf(M, __shfl_down(M, off));
            S += __shfl_down(S, off);
        }
        if (ln == 0) {
            int o = ob + w * 4 + oo;
            float* po = out_p + bq * 128;
            if (ACC) {
                po[o] += M;
                po[64 + o] += S * (1.f / 512.f);
            } else {
                po[o] = M;
                po[64 + o] = S * (1.f / 512.f);
                vec_out[bq * 64 + o] = M;
            }
        }
    }
}

// ---------------- corre_binar: f, masks ----------------
__global__ __launch_bounds__(256) void corre_kernel(
    const float* __restrict__ x, const float* __restrict__ x0vec,
    const float* __restrict__ w_reduce, const int* __restrict__ idx8,
    float* __restrict__ fbuf, float* __restrict__ masks)
{
    __shared__ float sxv[64], sq[64], ss[512], sfk[512];
    int bq = blockIdx.x, tid = threadIdx.x;
    int row = src_row(bq);
    const float* Xb = x + (size_t)row * 32768;
    if (tid < 64) sxv[tid] = x0vec[bq * 64 + tid];
    __syncthreads();
    if (tid < 64) {
        float a = 0.f;
        for (int c = 0; c < 64; ++c) a += w_reduce[tid * 64 + c] * sxv[c];
        sq[tid] = a;
    }
    __syncthreads();
    for (int i = tid; i < 512; i += 256) {
        float a = 0.f;
        for (int c = 0; c < 64; ++c) a += sq[c] * Xb[c * 512 + i];
        a *= 0.125f;                    // 1/sqrt(64)
        ss[i] = a;
        fbuf[bq * 512 + i] = a;
    }
    __syncthreads();
    for (int i = tid; i < 512; i += 256) {
        float a = ss[i];
        const int* ip = idx8 + ((size_t)bq * 512 + i) * 16;
        for (int q = 0; q < 8; ++q) a += ss[ip[q]];
        sfk[i] = a;
    }
    masks[bq * 512 + tid] = 1.0f;
    masks[bq * 512 + tid + 256] = 1.0f;
    __syncthreads();
    if (tid == 0) {
        float best = sfk[0]; int bi = 0;
        for (int i = 1; i < 512; ++i) if (sfk[i] > best) { best = sfk[i]; bi = i; }
        masks[bq * 512 + bi] = 0.f;
        const int* ip = idx8 + ((size_t)bq * 512 + bi) * 16;
        for (int q = 0; q < 8; ++q) masks[bq * 512 + ip[q]] = 0.f;
    }
}

// ---------------- erase1 fused with prep: x1e fp32 + h/l split + colnorms ----------------
__global__ __launch_bounds__(256) void erase1_kernel(
    const float* __restrict__ x, const float* __restrict__ masks,
    const float* __restrict__ fbuf,
    const float* __restrict__ w_e, const float* __restrict__ b_e,
    const float* __restrict__ g_e, const float* __restrict__ be_e,
    const float* __restrict__ m_e, const float* __restrict__ v_e,
    float* __restrict__ x1e,
    _Float16* __restrict__ H, _Float16* __restrict__ L, float* __restrict__ xn)
{
    __shared__ float sw[512];
    __shared__ float smk[512];
    __shared__ float red[256];
    __shared__ float sres[64];
    __shared__ float sy[64];
    __shared__ float lds[64 * 65];
    __shared__ float xnp[4 * 64];
    int bq = blockIdx.x, tid = threadIdx.x;
    int row = src_row(bq);
    const float* Xb = x + (size_t)row * 32768;
    float f0 = fbuf[bq * 512 + tid], f1 = fbuf[bq * 512 + tid + 256];
    float mk0 = masks[bq * 512 + tid], mk1 = masks[bq * 512 + tid + 256];
    smk[tid] = mk0; smk[tid + 256] = mk1;
    float s0 = f0 - (1.f - mk0) * 1e8f, s1 = f1 - (1.f - mk1) * 1e8f;
    red[tid] = fmaxf(s0, s1);
    __syncthreads();
    for (int off = 128; off >= 1; off >>= 1) {
        if (tid < off) red[tid] = fmaxf(red[tid], red[tid + off]);
        __syncthreads();
    }
    float mx = red[0];
    __syncthreads();
    float e0 = expf(s0 - mx), e1 = expf(s1 - mx);
    red[tid] = e0 + e1;
    __syncthreads();
    for (int off = 128; off >= 1; off >>= 1) {
        if (tid < off) red[tid] = red[tid] + red[tid + off];
        __syncthreads();
    }
    float inv = 1.f / red[0];
    __syncthreads();
    sw[tid] = e0 * inv; sw[tid + 256] = e1 * inv;
    __syncthreads();
    int c4 = tid >> 2, p4 = tid & 3;
    {
        float a = 0.f;
        const float* xr = Xb + c4 * 512 + p4 * 128;
        const float* wr = &sw[p4 * 128];
        for (int ii = 0; ii < 128; ++ii) a += xr[ii] * wr[ii];
        red[tid] = a;
    }
    __syncthreads();
    if (p4 == 0) sres[c4] = red[tid] + red[tid + 1] + red[tid + 2] + red[tid + 3];
    __syncthreads();
    if (tid < 64) {
        float a = b_e[tid];
        for (int cc = 0; cc < 64; ++cc) a += w_e[tid * 64 + cc] * sres[cc];
        float sc = g_e[tid] / sqrtf(v_e[tid] + EPS);
        sy[tid] = (a - m_e[tid]) * sc + be_e[tid];
    }
    // per col-tile: x1e = Xb*mask + sy  -> fp32 out + fp16 split + colnorm
    float* ob = x1e + (size_t)bq * 32768;
    for (int tt = 0; tt < 8; ++tt) {
        __syncthreads();                   // sy ready (tt=0); lds reusable (tt>0)
        for (int p = 0; p < 16; ++p) {
            int t = p * 256 + tid;
            int c = t >> 6, col = t & 63;
            float v = Xb[c * 512 + tt * 64 + col] * smk[tt * 64 + col] + sy[c];
            ob[c * 512 + tt * 64 + col] = v;
            lds[c * 65 + col] = v;
        }
        __syncthreads();
        int col = tid & 63, g = tid >> 6;
        half8 hv[2], lv[2];
        float s = 0.f;
        #pragma unroll
        for (int k = 0; k < 16; ++k) {
            int c = g * 16 + k;
            float v = lds[c * 65 + col];
            _Float16 h = (_Float16)v;
            _Float16 lo = (_Float16)(v - (float)h);
            hv[k >> 3][k & 7] = h;
            lv[k >> 3][k & 7] = lo;
            s += v * v;
        }
        size_t obase = ((size_t)bq * 512 + tt * 64 + col) * 64 + g * 16;
        *(half8*)(H + obase) = hv[0];
        *(half8*)(H + obase + 8) = hv[1];
        *(half8*)(L + obase) = lv[0];
        *(half8*)(L + obase + 8) = lv[1];
        xnp[g * 64 + col] = s;
        __syncthreads();
        if (tid < 64)
            xn[bq * 512 + tt * 64 + tid] =
                xnp[tid] + xnp[64 + tid] + xnp[128 + tid] + xnp[192 + tid];
    }
}

extern "C" void kernel_launch(void* const* d_in, const int* in_sizes, int n_in,
                              void* d_out, int out_size, void* d_ws, size_t ws_size,
                              hipStream_t stream)
{
    const float* x        = (const float*)d_in[0];
    const float* w_reduce = (const float*)d_in[1];
    const float* w_erase  = (const float*)d_in[2];
    const float* b_erase  = (const float*)d_in[3];
    const float* g_erase  = (const float*)d_in[4];
    const float* be_erase = (const float*)d_in[5];
    const float* m_erase  = (const float*)d_in[6];
    const float* v_erase  = (const float*)d_in[7];
    const float* w0 = (const float*)d_in[8];
    const float* g0 = (const float*)d_in[9];
    const float* b0 = (const float*)d_in[10];
    const float* m0 = (const float*)d_in[11];
    const float* v0 = (const float*)d_in[12];
    const float* w1 = (const float*)d_in[13];
    const float* g1 = (const float*)d_in[14];
    const float* b1 = (const float*)d_in[15];
    const float* m1 = (const float*)d_in[16];
    const float* v1 = (const float*)d_in[17];
    float* out = (float*)d_out;
    char* ws = (char*)d_ws;

    float* xbuf  = (float*)(ws);                 // 12.58 MB: x1e fp32 [c][n]
    float* AB    = (float*)(ws + 12582912);      // 25.17 MB, overlaid with h/l sets
    _Float16* h0 = (_Float16*)(ws + 12582912);   // 6.29 MB
    _Float16* l0 = (_Float16*)(ws + 18874368);   // 6.29 MB
    _Float16* h1 = (_Float16*)(ws + 25165824);   // 6.29 MB
    _Float16* l1 = (_Float16*)(ws + 31457280);   // 6.29 MB
    int*   idxA  = (int*)(ws + 37748736);        // 3.15 MB: k=10 idx (stride 16)
    int*   idx8  = (int*)(ws + 40894464);        // 3.15 MB: k=8 idx
    float* xn0   = (float*)(ws + 44040192);      // 192 KB
    float* xn1   = (float*)(ws + 44236800);      // 192 KB
    float* y0vec = (float*)(ws + 44433408);      // 24 KB
    float* x0vec = (float*)(ws + 44457984);      // 24 KB
    float* fbuf  = (float*)(ws + 44482560);      // 192 KB
    float* masks = (float*)(ws + 44679168);      // 192 KB  (total ~44.9 MB)

    (void)in_sizes; (void)n_in; (void)out_size; (void)ws_size;

    // x0 = x + y0vec (folded into prep/gemm)
    erase0_kernel<<<96, 256, 0, stream>>>(x, w_erase, b_erase, g_erase, be_erase, m_erase, v_erase, y0vec);
    // fused prep for x0 (half 0) and x1seq (half 1)
    prep_kernel<<<1536, 256, 0, stream>>>(x, y0vec, h0, l0, xn0, h1, l1, xn1);
    // fused kNN: k=10 on x0 -> idxA ; k=8 on x1seq -> idx8
    knn_kernel<<<1536, 256, 0, stream>>>(h0, l0, xn0, idxA, 10, h1, l1, xn1, idx8, 8);
    // branch 0 (gemm overwrites h/l region; knn already consumed it)
    gemm_kernel<<<768, 256, 0, stream>>>(x, w0, y0vec, AB);
    branch_reduce_kernel<0><<<dim3(96, 4), 256, 0, stream>>>(AB, idxA, g0, b0, m0, v0, out, x0vec);
    // corre_binar on x1seq
    corre_kernel<<<96, 256, 0, stream>>>(x, x0vec, w_reduce, idx8, fbuf, masks);
    // x1e = erase(x1seq, masks, f)  + fused fp16 split/colnorm (overwrites AB region)
    erase1_kernel<<<96, 256, 0, stream>>>(x, masks, fbuf, w_erase, b_erase, g_erase, be_erase, m_erase, v_erase,
                                          xbuf, h0, l0, xn0);
    // branch 1
    knn_kernel<<<768, 256, 0, stream>>>(h0, l0, xn0, idxA, 10, h0, l0, xn0, idxA, 10);
    gemm_kernel<<<768, 256, 0, stream>>>(xbuf, w1, nullptr, AB);
    branch_reduce_kernel<1><<<dim3(96, 4), 256, 0, stream>>>(AB, idxA, g1, b1, m1, v1, out, nullptr);
}

// Round 6
// 408.634 us; speedup vs baseline: 2.2813x; 1.1396x over previous
//
#include <hip/hip_runtime.h>
#include <math.h>

#define EPS 1e-5f

typedef _Float16 half8 __attribute__((ext_vector_type(8)));
typedef float f32x4 __attribute__((ext_vector_type(4)));

// bq in [0,96): b = bq/12, t = bq%12; x1seq row = b*12 + min(t+1, 11)
__device__ __forceinline__ int src_row(int bq) {
    int b = bq / 12, t = bq - b * 12;
    int t2 = (t + 1 < 12) ? (t + 1) : 11;
    return b * 12 + t2;
}

// ---------------- erase0: y0vec[bq][o] = BN(W_e @ mean_n(x) + b_e) ----------------
__global__ __launch_bounds__(256) void erase0_kernel(
    const float* __restrict__ x, const float* __restrict__ w_e,
    const float* __restrict__ b_e, const float* __restrict__ g_e,
    const float* __restrict__ be_e, const float* __restrict__ m_e,
    const float* __restrict__ v_e, float* __restrict__ y0vec)
{
    __shared__ float part[256];
    __shared__ float res[64];
    int bq = blockIdx.x, tid = threadIdx.x;
    int c = tid >> 2, p = tid & 3;
    const float* xb = x + (size_t)bq * 32768 + c * 512 + p * 128;
    float acc = 0.f;
    for (int ii = 0; ii < 128; ii += 4) {
        float4 v = *(const float4*)(xb + ii);
        acc += v.x + v.y + v.z + v.w;
    }
    part[tid] = acc;
    __syncthreads();
    if (p == 0) res[c] = (part[tid] + part[tid+1] + part[tid+2] + part[tid+3]) * (1.f/512.f);
    __syncthreads();
    if (tid < 64) {
        float a = b_e[tid];
        for (int cc = 0; cc < 64; ++cc) a += w_e[tid*64+cc] * res[cc];
        float s = g_e[tid] / sqrtf(v_e[tid] + EPS);
        y0vec[bq*64 + tid] = (a - m_e[tid]) * s + be_e[tid];
    }
}

// ---------------- prep dual + W' split ----------------
// grid = 1536. blockIdx = q*96 + bq, q=0..15: ct=q&7, half=q>>3.
// half 0: row=bq, +vec (x0);  half 1: row=src_row(bq) (x1seq).
// blocks raw<2 additionally split W' = [W1; W2-W1] to fp16 h/l for branch raw.
__global__ __launch_bounds__(256) void prep_kernel(
    const float* __restrict__ X, const float* __restrict__ vec,
    _Float16* __restrict__ H0, _Float16* __restrict__ L0, float* __restrict__ xn0,
    _Float16* __restrict__ H1, _Float16* __restrict__ L1, float* __restrict__ xn1,
    const float* __restrict__ w0, const float* __restrict__ w1,
    _Float16* __restrict__ wh0, _Float16* __restrict__ wl0,
    _Float16* __restrict__ wh1, _Float16* __restrict__ wl1)
{
    __shared__ float lds[64 * 65];     // [c][col] pad
    __shared__ float xnp[4 * 64];
    int raw = blockIdx.x;
    int bq = raw % 96;
    int q = raw / 96;
    int ct = q & 7, half = q >> 3;
    int row = half ? src_row(bq) : bq;
    _Float16* H = half ? H1 : H0;
    _Float16* L = half ? L1 : L0;
    float* xn = half ? xn1 : xn0;
    const float* vp = half ? nullptr : vec;
    const float* Xb = X + (size_t)row * 32768 + ct * 64;
    int tid = threadIdx.x;
    for (int p = 0; p < 16; ++p) {
        int t = p * 256 + tid;
        int c = t >> 6, col = t & 63;
        float v = Xb[c * 512 + col];
        if (vp) v += vp[bq * 64 + c];
        lds[c * 65 + col] = v;
    }
    __syncthreads();
    int col = tid & 63, g = tid >> 6;       // g: group of 16 channels
    half8 hv[2], lv[2];
    float s = 0.f;
    #pragma unroll
    for (int k = 0; k < 16; ++k) {
        int c = g * 16 + k;
        float v = lds[c * 65 + col];
        _Float16 h = (_Float16)v;
        _Float16 lo = (_Float16)(v - (float)h);
        hv[k >> 3][k & 7] = h;
        lv[k >> 3][k & 7] = lo;
        s += v * v;
    }
    size_t obase = ((size_t)bq * 512 + ct * 64 + col) * 64 + g * 16;
    *(half8*)(H + obase) = hv[0];
    *(half8*)(H + obase + 8) = hv[1];
    *(half8*)(L + obase) = lv[0];
    *(half8*)(L + obase + 8) = lv[1];
    xnp[g * 64 + col] = s;
    __syncthreads();
    if (tid < 64)
        xn[bq * 512 + ct * 64 + tid] =
            xnp[tid] + xnp[64 + tid] + xnp[128 + tid] + xnp[192 + tid];
    // W' split for branch raw (raw<2): Wp[o][c], o<64: W1, o>=64: W2-W1
    if (raw < 2) {
        const float* W = raw ? w1 : w0;
        _Float16* WH = raw ? wh1 : wh0;
        _Float16* WL = raw ? wl1 : wl0;
        for (int t = tid; t < 8192; t += 256) {
            int o = t >> 6, c = t & 63;
            float v = (o < 64) ? W[o * 128 + c]
                               : (W[(o - 64) * 128 + 64 + c] - W[(o - 64) * 128 + c]);
            _Float16 h = (_Float16)v;
            WH[t] = h;
            WL[t] = (_Float16)(v - (float)h);
        }
    }
}

// ---------------- kNN: transposed MFMA + Batcher sort-16 selection (dual-capable) ----------------
// grid = 1536 (dual) or 768 (single). blockIdx = q*96+bq, itile=q&7, half=q>>3.
__global__ __launch_bounds__(256) void knn_kernel(
    const _Float16* __restrict__ H0, const _Float16* __restrict__ L0,
    const float* __restrict__ xn0, int* __restrict__ idx0, int k0,
    const _Float16* __restrict__ H1, const _Float16* __restrict__ L1,
    const float* __restrict__ xn1, int* __restrict__ idx1, int k1)
{
    __shared__ float          ldsMV[4][64 * 17];   // per wave: 64 lists x 16 vals, pad 17
    __shared__ unsigned short ldsMJ[4][64 * 17];   // ushort idx -> 26112 B total, 6 blocks/CU
    int raw = blockIdx.x;
    int bq = raw % 96;
    int q = raw / 96;
    int itile = q & 7, half = q >> 3;
    const _Float16* H = half ? H1 : H0;
    const _Float16* L = half ? L1 : L0;
    const float* xn = half ? xn1 : xn0;
    int* idx_out = half ? idx1 : idx0;
    int K = half ? k1 : k0;
    int tid = threadIdx.x, w = tid >> 6, l = tid & 63;
    int lane16 = l & 15, quad = l >> 4;
    const size_t base = (size_t)bq * 512 * 64;
    int irow = itile * 64 + w * 16 + lane16;
    const _Float16* Hi = H + base + (size_t)irow * 64 + quad * 8;
    const _Float16* Li = L + base + (size_t)irow * 64 + quad * 8;
    half8 Bh0 = *(const half8*)(Hi);
    half8 Bh1 = *(const half8*)(Hi + 32);
    half8 Bl0 = *(const half8*)(Li);
    half8 Bl1 = *(const half8*)(Li + 32);

    float kv[16]; int kj[16];              // running top-16, ascending (kv[15]=best)
    #pragma unroll
    for (int qq = 0; qq < 16; ++qq) { kv[qq] = -3.4e38f; kj[qq] = 0; }

    auto cas_asc = [](float& va, int& ja, float& vb, int& jb2) {
        bool sw = va > vb;
        float tv = va; int tj = ja;
        va = sw ? vb : va; ja = sw ? jb2 : ja;
        vb = sw ? tv : vb; jb2 = sw ? tj : jb2;
    };

    const float* xnb = xn + bq * 512;
    for (int jt = 0; jt < 8; ++jt) {
        float d[16]; int jd[16];
        #pragma unroll
        for (int g = 0; g < 4; ++g) {
            int jrow = jt * 64 + g * 16 + lane16;
            const _Float16* Hj = H + base + (size_t)jrow * 64 + quad * 8;
            const _Float16* Lj = L + base + (size_t)jrow * 64 + quad * 8;
            half8 Ah0 = *(const half8*)(Hj);
            half8 Ah1 = *(const half8*)(Hj + 32);
            half8 Al0 = *(const half8*)(Lj);
            half8 Al1 = *(const half8*)(Lj + 32);
            f32x4 acc = {0.f, 0.f, 0.f, 0.f};
            acc = __builtin_amdgcn_mfma_f32_16x16x32_f16(Ah0, Bh0, acc, 0, 0, 0);
            acc = __builtin_amdgcn_mfma_f32_16x16x32_f16(Ah1, Bh1, acc, 0, 0, 0);
            acc = __builtin_amdgcn_mfma_f32_16x16x32_f16(Al0, Bh0, acc, 0, 0, 0);
            acc = __builtin_amdgcn_mfma_f32_16x16x32_f16(Al1, Bh1, acc, 0, 0, 0);
            acc = __builtin_amdgcn_mfma_f32_16x16x32_f16(Ah0, Bl0, acc, 0, 0, 0);
            acc = __builtin_amdgcn_mfma_f32_16x16x32_f16(Ah1, Bl1, acc, 0, 0, 0);
            // (L*L term dropped: ~3e-7, below fp32 accumulation noise)
            int jb = jt * 64 + g * 16 + quad * 4;   // lane holds j = jb..jb+3, col = irow
            float4 xn4 = *(const float4*)&xnb[jb];
            d[g * 4 + 0] = 2.f * acc[0] - xn4.x; jd[g * 4 + 0] = jb + 0;
            d[g * 4 + 1] = 2.f * acc[1] - xn4.y; jd[g * 4 + 1] = jb + 1;
            d[g * 4 + 2] = 2.f * acc[2] - xn4.z; jd[g * 4 + 2] = jb + 2;
            d[g * 4 + 3] = 2.f * acc[3] - xn4.w; jd[g * 4 + 3] = jb + 3;
        }
        // Batcher odd-even mergesort-16 ascending: 63 CAS, fully static after unroll
        #pragma unroll
        for (int p = 1; p < 16; p <<= 1) {
            #pragma unroll
            for (int k = p; k >= 1; k >>= 1) {
                #pragma unroll
                for (int j = k & (p - 1); j + k < 16; j += 2 * k) {
                    #pragma unroll
                    for (int i = 0; i < k; ++i) {
                        if ((i + j + k < 16) &&
                            ((i + j) / (2 * p) == (i + j + k) / (2 * p)))
                            cas_asc(d[i + j], jd[i + j], d[i + j + k], jd[i + j + k]);
                    }
                }
            }
        }
        // exact top-16 of (kv ∪ d): max-trick (result bitonic), then bitonic clean
        #pragma unroll
        for (int i = 0; i < 16; ++i) {
            bool take = kv[i] >= d[15 - i];
            kv[i] = take ? kv[i] : d[15 - i];
            kj[i] = take ? kj[i] : jd[15 - i];
        }
        #pragma unroll
        for (int jj = 8; jj > 0; jj >>= 1) {
            #pragma unroll
            for (int i = 0; i < 16; ++i) {
                int lo = i ^ jj;
                if (lo > i) cas_asc(kv[i], kj[i], kv[lo], kj[lo]);
            }
        }
    }
    // dump sorted-16 per quad (pad-17 stride), merge 4 lists per row
    #pragma unroll
    for (int qq = 0; qq < 16; ++qq) {
        ldsMV[w][(lane16 * 4 + quad) * 17 + qq] = kv[qq];
        ldsMJ[w][(lane16 * 4 + quad) * 17 + qq] = (unsigned short)kj[qq];
    }
    __syncthreads();
    if (quad == 0) {
        const float* MV = &ldsMV[w][lane16 * 68];
        const unsigned short* MJ = &ldsMJ[w][lane16 * 68];
        int p0 = 15, p1 = 15, p2 = 15, p3 = 15;
        int* op = idx_out + ((size_t)bq * 512 + irow) * 16;
        for (int t = 0; t < K; ++t) {
            float bv = -3.4e38f; int bj = 0x7fffffff; int bc = -1;
            { float v = MV[p0]; int j = MJ[p0];
              if (v > bv || (v == bv && j < bj)) { bv = v; bj = j; bc = 0; } }
            { float v = MV[17 + p1]; int j = MJ[17 + p1];
              if (v > bv || (v == bv && j < bj)) { bv = v; bj = j; bc = 1; } }
            { float v = MV[34 + p2]; int j = MJ[34 + p2];
              if (v > bv || (v == bv && j < bj)) { bv = v; bj = j; bc = 2; } }
            { float v = MV[51 + p3]; int j = MJ[51 + p3];
              if (v > bv || (v == bv && j < bj)) { bv = v; bj = j; bc = 3; } }
            if (bc == 0) --p0; else if (bc == 1) --p1; else if (bc == 2) --p2; else --p3;
            op[t] = bj;
        }
    }
}

// ---------------- MFMA gemm: AB[bq] = W' (128x64) @ X (64x512), split-fp16 ----------------
// blockIdx = itile*96 + bq (XCD swizzle). No LDS, no barriers.
// Wave w: o-tiles {2w, 2w+1} x 4 i-tiles; D[row=quad*4+r -> o, col=lane16 -> i].
__global__ __launch_bounds__(256) void gemm_mfma_kernel(
    const _Float16* __restrict__ H, const _Float16* __restrict__ L,
    const _Float16* __restrict__ WH, const _Float16* __restrict__ WL,
    float* __restrict__ AB)
{
    int raw = blockIdx.x;
    int bq = raw % 96;
    int itile = raw / 96;
    int tid = threadIdx.x, w = tid >> 6, l = tid & 63;
    int lane16 = l & 15, quad = l >> 4;
    const size_t xbase = (size_t)bq * 32768;
    half8 Bh0[4], Bh1[4], Bl0[4], Bl1[4];
    #pragma unroll
    for (int it = 0; it < 4; ++it) {
        size_t off = xbase + (size_t)(itile * 64 + it * 16 + lane16) * 64 + quad * 8;
        Bh0[it] = *(const half8*)(H + off);
        Bh1[it] = *(const half8*)(H + off + 32);
        Bl0[it] = *(const half8*)(L + off);
        Bl1[it] = *(const half8*)(L + off + 32);
    }
    float* ABb = AB + (size_t)bq * 65536 + itile * 64;
    #pragma unroll
    for (int oo = 0; oo < 2; ++oo) {
        int ot = w * 2 + oo;
        size_t woff = (size_t)(ot * 16 + lane16) * 64 + quad * 8;
        half8 Ah0 = *(const half8*)(WH + woff);
        half8 Ah1 = *(const half8*)(WH + woff + 32);
        half8 Al0 = *(const half8*)(WL + woff);
        half8 Al1 = *(const half8*)(WL + woff + 32);
        #pragma unroll
        for (int it = 0; it < 4; ++it) {
            f32x4 acc = {0.f, 0.f, 0.f, 0.f};
            acc = __builtin_amdgcn_mfma_f32_16x16x32_f16(Ah0, Bh0[it], acc, 0, 0, 0);
            acc = __builtin_amdgcn_mfma_f32_16x16x32_f16(Ah1, Bh1[it], acc, 0, 0, 0);
            acc = __builtin_amdgcn_mfma_f32_16x16x32_f16(Ah0, Bl0[it], acc, 0, 0, 0);
            acc = __builtin_amdgcn_mfma_f32_16x16x32_f16(Ah1, Bl1[it], acc, 0, 0, 0);
            acc = __builtin_amdgcn_mfma_f32_16x16x32_f16(Al0, Bh0[it], acc, 0, 0, 0);
            acc = __builtin_amdgcn_mfma_f32_16x16x32_f16(Al1, Bh1[it], acc, 0, 0, 0);
            #pragma unroll
            for (int r = 0; r < 4; ++r)
                ABb[(size_t)(ot * 16 + quad * 4 + r) * 512 + it * 16 + lane16] = acc[r];
        }
    }
}

// ---------------- branch epilogue: grid (96,4), 16 o's per block ----------------
template<int ACC>
__global__ __launch_bounds__(256) void branch_reduce_kernel(
    const float* __restrict__ AB, const int* __restrict__ idx,
    const float* __restrict__ g, const float* __restrict__ bb,
    const float* __restrict__ mm, const float* __restrict__ vv,
    float* __restrict__ out_p, float* __restrict__ vec_out)
{
    __shared__ float ldsA[16 * 512];       // 32 KB: A-chunk [o][i]
    __shared__ int   ldsIdx[512 * 10];     // 20 KB
    int bq = blockIdx.x, ob = blockIdx.y * 16;
    int tid = threadIdx.x;
    int w = tid >> 6, ln = tid & 63;
    for (int p = 0; p < 20; ++p) {
        int t = p * 256 + tid;
        int i = t / 10, q = t - i * 10;
        ldsIdx[t] = idx[((size_t)bq * 512 + i) * 16 + q];
    }
    const float* ABb = AB + (size_t)bq * 65536;
    for (int p = 0; p < 8; ++p) {
        int t = p * 256 + tid;             // float4 index into 16*512
        int o = t >> 7, i4 = t & 127;
        *(float4*)&ldsA[o * 512 + i4 * 4] = *(const float4*)&ABb[(size_t)(ob + o) * 512 + i4 * 4];
    }
    float ssr[4], str[4];
    #pragma unroll
    for (int oo = 0; oo < 4; ++oo) {
        int o = ob + w * 4 + oo;
        float sc = g[o] / sqrtf(vv[o] + EPS);
        ssr[oo] = sc;
        str[oo] = bb[o] - mm[o] * sc;
    }
    __syncthreads();
    float omax[4], osum[4];
    #pragma unroll
    for (int oo = 0; oo < 4; ++oo) { omax[oo] = -3.4e38f; osum[oo] = 0.f; }
    const float* Aw = ldsA + (w * 4) * 512;
    for (int s = 0; s < 8; ++s) {
        int i = ln + 64 * s;
        int idr[10];
        const int* ip = &ldsIdx[i * 10];
        #pragma unroll
        for (int q = 0; q < 10; ++q) idr[q] = ip[q];
        #pragma unroll
        for (int oo = 0; oo < 4; ++oo) {
            const float* Ao = Aw + oo * 512;
            float mx = Ao[idr[0]];
            #pragma unroll
            for (int q = 1; q < 10; ++q) mx = fmaxf(mx, Ao[idr[q]]);
            float Bv = ABb[(size_t)(64 + ob + w * 4 + oo) * 512 + i];
            float val = (mx + Bv) * ssr[oo] + str[oo];
            float y = val > 0.f ? val : 0.2f * val;
            omax[oo] = fmaxf(omax[oo], y);
            osum[oo] += y;
        }
    }
    #pragma unroll
    for (int oo = 0; oo < 4; ++oo) {
        float M = omax[oo], S = osum[oo];
        #pragma unroll
        for (int off = 32; off >= 1; off >>= 1) {
            M = fmaxf(M, __shfl_down(M, off));
            S += __shfl_down(S, off);
        }
        if (ln == 0) {
            int o = ob + w * 4 + oo;
            float* po = out_p + bq * 128;
            if (ACC) {
                po[o] += M;
                po[64 + o] += S * (1.f / 512.f);
            } else {
                po[o] = M;
                po[64 + o] = S * (1.f / 512.f);
                vec_out[bq * 64 + o] = M;
            }
        }
    }
}

// ---------------- corre_binar: f, masks ----------------
__global__ __launch_bounds__(256) void corre_kernel(
    const float* __restrict__ x, const float* __restrict__ x0vec,
    const float* __restrict__ w_reduce, const int* __restrict__ idx8,
    float* __restrict__ fbuf, float* __restrict__ masks)
{
    __shared__ float sxv[64], sq[64], ss[512], sfk[512];
    int bq = blockIdx.x, tid = threadIdx.x;
    int row = src_row(bq);
    const float* Xb = x + (size_t)row * 32768;
    if (tid < 64) sxv[tid] = x0vec[bq * 64 + tid];
    __syncthreads();
    if (tid < 64) {
        float a = 0.f;
        for (int c = 0; c < 64; ++c) a += w_reduce[tid * 64 + c] * sxv[c];
        sq[tid] = a;
    }
    __syncthreads();
    for (int i = tid; i < 512; i += 256) {
        float a = 0.f;
        for (int c = 0; c < 64; ++c) a += sq[c] * Xb[c * 512 + i];
        a *= 0.125f;                    // 1/sqrt(64)
        ss[i] = a;
        fbuf[bq * 512 + i] = a;
    }
    __syncthreads();
    for (int i = tid; i < 512; i += 256) {
        float a = ss[i];
        const int* ip = idx8 + ((size_t)bq * 512 + i) * 16;
        for (int q = 0; q < 8; ++q) a += ss[ip[q]];
        sfk[i] = a;
    }
    masks[bq * 512 + tid] = 1.0f;
    masks[bq * 512 + tid + 256] = 1.0f;
    __syncthreads();
    if (tid == 0) {
        float best = sfk[0]; int bi = 0;
        for (int i = 1; i < 512; ++i) if (sfk[i] > best) { best = sfk[i]; bi = i; }
        masks[bq * 512 + bi] = 0.f;
        const int* ip = idx8 + ((size_t)bq * 512 + bi) * 16;
        for (int q = 0; q < 8; ++q) masks[bq * 512 + ip[q]] = 0.f;
    }
}

// ---------------- erase1 fused with prep: x1e -> h/l split + colnorms (no fp32 out) ----------------
__global__ __launch_bounds__(256) void erase1_kernel(
    const float* __restrict__ x, const float* __restrict__ masks,
    const float* __restrict__ fbuf,
    const float* __restrict__ w_e, const float* __restrict__ b_e,
    const float* __restrict__ g_e, const float* __restrict__ be_e,
    const float* __restrict__ m_e, const float* __restrict__ v_e,
    _Float16* __restrict__ H, _Float16* __restrict__ L, float* __restrict__ xn)
{
    __shared__ float sw[512];
    __shared__ float smk[512];
    __shared__ float red[256];
    __shared__ float sres[64];
    __shared__ float sy[64];
    __shared__ float lds[64 * 65];
    __shared__ float xnp[4 * 64];
    int bq = blockIdx.x, tid = threadIdx.x;
    int row = src_row(bq);
    const float* Xb = x + (size_t)row * 32768;
    float f0 = fbuf[bq * 512 + tid], f1 = fbuf[bq * 512 + tid + 256];
    float mk0 = masks[bq * 512 + tid], mk1 = masks[bq * 512 + tid + 256];
    smk[tid] = mk0; smk[tid + 256] = mk1;
    float s0 = f0 - (1.f - mk0) * 1e8f, s1 = f1 - (1.f - mk1) * 1e8f;
    red[tid] = fmaxf(s0, s1);
    __syncthreads();
    for (int off = 128; off >= 1; off >>= 1) {
        if (tid < off) red[tid] = fmaxf(red[tid], red[tid + off]);
        __syncthreads();
    }
    float mx = red[0];
    __syncthreads();
    float e0 = expf(s0 - mx), e1 = expf(s1 - mx);
    red[tid] = e0 + e1;
    __syncthreads();
    for (int off = 128; off >= 1; off >>= 1) {
        if (tid < off) red[tid] = red[tid] + red[tid + off];
        __syncthreads();
    }
    float inv = 1.f / red[0];
    __syncthreads();
    sw[tid] = e0 * inv; sw[tid + 256] = e1 * inv;
    __syncthreads();
    int c4 = tid >> 2, p4 = tid & 3;
    {
        float a = 0.f;
        const float* xr = Xb + c4 * 512 + p4 * 128;
        const float* wr = &sw[p4 * 128];
        for (int ii = 0; ii < 128; ++ii) a += xr[ii] * wr[ii];
        red[tid] = a;
    }
    __syncthreads();
    if (p4 == 0) sres[c4] = red[tid] + red[tid + 1] + red[tid + 2] + red[tid + 3];
    __syncthreads();
    if (tid < 64) {
        float a = b_e[tid];
        for (int cc = 0; cc < 64; ++cc) a += w_e[tid * 64 + cc] * sres[cc];
        float sc = g_e[tid] / sqrtf(v_e[tid] + EPS);
        sy[tid] = (a - m_e[tid]) * sc + be_e[tid];
    }
    // per col-tile: x1e = Xb*mask + sy -> fp16 split + colnorm
    for (int tt = 0; tt < 8; ++tt) {
        __syncthreads();                   // sy ready (tt=0); lds reusable (tt>0)
        for (int p = 0; p < 16; ++p) {
            int t = p * 256 + tid;
            int c = t >> 6, col = t & 63;
            float v = Xb[c * 512 + tt * 64 + col] * smk[tt * 64 + col] + sy[c];
            lds[c * 65 + col] = v;
        }
        __syncthreads();
        int col = tid & 63, g = tid >> 6;
        half8 hv[2], lv[2];
        float s = 0.f;
        #pragma unroll
        for (int k = 0; k < 16; ++k) {
            int c = g * 16 + k;
            float v = lds[c * 65 + col];
            _Float16 h = (_Float16)v;
            _Float16 lo = (_Float16)(v - (float)h);
            hv[k >> 3][k & 7] = h;
            lv[k >> 3][k & 7] = lo;
            s += v * v;
        }
        size_t obase = ((size_t)bq * 512 + tt * 64 + col) * 64 + g * 16;
        *(half8*)(H + obase) = hv[0];
        *(half8*)(H + obase + 8) = hv[1];
        *(half8*)(L + obase) = lv[0];
        *(half8*)(L + obase + 8) = lv[1];
        xnp[g * 64 + col] = s;
        __syncthreads();
        if (tid < 64)
            xn[bq * 512 + tt * 64 + tid] =
                xnp[tid] + xnp[64 + tid] + xnp[128 + tid] + xnp[192 + tid];
    }
}

extern "C" void kernel_launch(void* const* d_in, const int* in_sizes, int n_in,
                              void* d_out, int out_size, void* d_ws, size_t ws_size,
                              hipStream_t stream)
{
    const float* x        = (const float*)d_in[0];
    const float* w_reduce = (const float*)d_in[1];
    const float* w_erase  = (const float*)d_in[2];
    const float* b_erase  = (const float*)d_in[3];
    const float* g_erase  = (const float*)d_in[4];
    const float* be_erase = (const float*)d_in[5];
    const float* m_erase  = (const float*)d_in[6];
    const float* v_erase  = (const float*)d_in[7];
    const float* w0 = (const float*)d_in[8];
    const float* g0 = (const float*)d_in[9];
    const float* b0 = (const float*)d_in[10];
    const float* m0 = (const float*)d_in[11];
    const float* v0 = (const float*)d_in[12];
    const float* w1 = (const float*)d_in[13];
    const float* g1 = (const float*)d_in[14];
    const float* b1 = (const float*)d_in[15];
    const float* m1 = (const float*)d_in[16];
    const float* v1 = (const float*)d_in[17];
    float* out = (float*)d_out;
    char* ws = (char*)d_ws;

    // Layout (lifetime-overlaid):
    _Float16* h0 = (_Float16*)(ws);              // [0, 6.29M)   x0 / x1e high
    _Float16* l0 = (_Float16*)(ws + 6291456);    // [6.29, 12.58M)
    _Float16* h1 = (_Float16*)(ws + 12582912);   // [12.58, 18.87M)  x1seq high (dies after dual-knn)
    _Float16* l1 = (_Float16*)(ws + 18874368);   // [18.87, 25.17M)
    float* AB    = (float*)(ws + 12582912);      // [12.58, 37.75M)  overlays h1/l1 (written after dual-knn)
    int*   idxA  = (int*)(ws + 37748736);        // 3.15 MB
    int*   idx8  = (int*)(ws + 40894464);        // 3.15 MB
    float* xn0   = (float*)(ws + 44040192);      // 192 KB
    float* xn1   = (float*)(ws + 44236800);      // 192 KB
    float* y0vec = (float*)(ws + 44433408);      // 24 KB
    float* x0vec = (float*)(ws + 44457984);      // 24 KB
    float* fbuf  = (float*)(ws + 44482560);      // 192 KB
    float* masks = (float*)(ws + 44679168);      // 192 KB
    _Float16* wh0 = (_Float16*)(ws + 44875776);  // 16 KB
    _Float16* wl0 = (_Float16*)(ws + 44892160);  // 16 KB
    _Float16* wh1 = (_Float16*)(ws + 44908544);  // 16 KB
    _Float16* wl1 = (_Float16*)(ws + 44924928);  // 16 KB  (end ~44.94 MB)

    (void)in_sizes; (void)n_in; (void)out_size; (void)ws_size;

    // x0 = x + y0vec (folded into prep)
    erase0_kernel<<<96, 256, 0, stream>>>(x, w_erase, b_erase, g_erase, be_erase, m_erase, v_erase, y0vec);
    // fused prep for x0 (half 0), x1seq (half 1), + W' splits
    prep_kernel<<<1536, 256, 0, stream>>>(x, y0vec, h0, l0, xn0, h1, l1, xn1,
                                          w0, w1, wh0, wl0, wh1, wl1);
    // fused kNN: k=10 on x0 -> idxA ; k=8 on x1seq -> idx8
    knn_kernel<<<1536, 256, 0, stream>>>(h0, l0, xn0, idxA, 10, h1, l1, xn1, idx8, 8);
    // branch 0 (gemm writes AB over dead h1/l1)
    gemm_mfma_kernel<<<768, 256, 0, stream>>>(h0, l0, wh0, wl0, AB);
    branch_reduce_kernel<0><<<dim3(96, 4), 256, 0, stream>>>(AB, idxA, g0, b0, m0, v0, out, x0vec);
    // corre_binar on x1seq
    corre_kernel<<<96, 256, 0, stream>>>(x, x0vec, w_reduce, idx8, fbuf, masks);
    // x1e = erase(x1seq, masks, f): rewrite h0/l0/xn0 in place
    erase1_kernel<<<96, 256, 0, stream>>>(x, masks, fbuf, w_erase, b_erase, g_erase, be_erase, m_erase, v_erase,
                                          h0, l0, xn0);
    // branch 1
    knn_kernel<<<768, 256, 0, stream>>>(h0, l0, xn0, idxA, 10, h0, l0, xn0, idxA, 10);
    gemm_mfma_kernel<<<768, 256, 0, stream>>>(h0, l0, wh1, wl1, AB);
    branch_reduce_kernel<1><<<dim3(96, 4), 256, 0, stream>>>(AB, idxA, g1, b1, m1, v1, out, nullptr);
}